// Round 2
// baseline (235.919 us; speedup 1.0000x reference)
//
#include <hip/hip_runtime.h>
#include <hip/hip_bf16.h>
#include <stdint.h>

#define DEV __device__ __forceinline__

typedef short short8 __attribute__((ext_vector_type(8)));
typedef float floatx4 __attribute__((ext_vector_type(4)));

constexpr int D = 256;
constexpr int NTOK = 8192;
constexpr int MTOT = 4 * NTOK;  // 32768 rows total

DEV void gl_lds16(const void* g, void* l) {
  __builtin_amdgcn_global_load_lds(
      (const __attribute__((address_space(1))) void*)g,
      (__attribute__((address_space(3))) void*)l, 16, 0, 0);
}

DEV float bflo(uint32_t u) { return __uint_as_float(u << 16); }
DEV float bfhi(uint32_t u) { return __uint_as_float(u & 0xffff0000u); }
DEV uint32_t packbf(float a, float b) {
  uint16_t xa = __builtin_bit_cast(uint16_t, __float2bfloat16(a));
  uint16_t xb = __builtin_bit_cast(uint16_t, __float2bfloat16(b));
  return (uint32_t)xa | ((uint32_t)xb << 16);
}

// ---------------- Kernel 0: fp32 -> bf16 conversion of phi, Wq, Wk, Wv ----------------
// dst is one contiguous bf16 region: [phi16 | Wq16 | Wk16 | Wv16]
constexpr int PHI_E = MTOT * D;          // 8388608
constexpr int W_E = D * D;               // 65536
__global__ __launch_bounds__(256) void convert(
    const float* __restrict__ phi, const float* __restrict__ Wq,
    const float* __restrict__ Wk, const float* __restrict__ Wv,
    uint32_t* __restrict__ dst) {
  const int idx2 = blockIdx.x * 256 + threadIdx.x;  // pair index
  const int e0 = idx2 * 2;
  float2 v;
  if (e0 < PHI_E) {
    v = ((const float2*)phi)[idx2];
  } else {
    int r = e0 - PHI_E;
    if (r < W_E) v = ((const float2*)Wq)[r >> 1];
    else if (r < 2 * W_E) v = ((const float2*)Wk)[(r - W_E) >> 1];
    else v = ((const float2*)Wv)[(r - 2 * W_E) >> 1];
  }
  dst[idx2] = packbf(v.x, v.y);
}

// ---------------- Kernel 1: fused QKV GEMM  out = phi @ W^T + bias (bf16 out) ----------------
__global__ __launch_bounds__(256, 2) void gemm_qkv(
    const __hip_bfloat16* __restrict__ phi,
    const __hip_bfloat16* __restrict__ Wq, const float* __restrict__ bq,
    const __hip_bfloat16* __restrict__ Wk, const float* __restrict__ bk,
    const __hip_bfloat16* __restrict__ Wv, const float* __restrict__ bv,
    __hip_bfloat16* __restrict__ Qb, __hip_bfloat16* __restrict__ Kb,
    __hip_bfloat16* __restrict__ Vb) {
  __shared__ __align__(16) char As[8192];
  __shared__ __align__(16) char Bs[8192];
  const int t = threadIdx.x, lane = t & 63, wid = t >> 6;
  const int wm = (wid & 1) * 64, wn = (wid >> 1) * 64;
  const int l16 = lane & 15, q4 = lane >> 4;
  const int m0 = blockIdx.x * 128;
  const int ct = blockIdx.y;          // 0..5
  const int mat = ct >> 1;            // 0=Q 1=K 2=V
  const int n0 = (ct & 1) * 128;
  const __hip_bfloat16* W = (mat == 0) ? Wq : (mat == 1) ? Wk : Wv;
  const float* bias        = (mat == 0) ? bq : (mat == 1) ? bk : bv;
  __hip_bfloat16* Out      = (mat == 0) ? Qb : (mat == 1) ? Kb : Vb;

  floatx4 acc[4][4] = {};

  const int srow = wid * 16 + (lane >> 2);
  const int skoff = (lane & 3) * 8;
  const __hip_bfloat16* gA = phi + (size_t)(m0 + srow) * D + skoff;
  const __hip_bfloat16* gB = W + (size_t)(n0 + srow) * D + skoff;
  char* lA = As + srow * 64 + skoff * 2;
  char* lB = Bs + srow * 64 + skoff * 2;

  for (int kt = 0; kt < 256; kt += 32) {
    gl_lds16(gA + kt, lA);
    gl_lds16(gA + kt + 64 * D, lA + 4096);
    gl_lds16(gB + kt, lB);
    gl_lds16(gB + kt + 64 * D, lB + 4096);
    __syncthreads();
    short8 af[4], bf8[4];
#pragma unroll
    for (int i = 0; i < 4; i++) {
      af[i]  = *(const short8*)(As + (wm + i * 16 + l16) * 64 + q4 * 16);
      bf8[i] = *(const short8*)(Bs + (wn + i * 16 + l16) * 64 + q4 * 16);
    }
#pragma unroll
    for (int i = 0; i < 4; i++)
#pragma unroll
      for (int j = 0; j < 4; j++)
        acc[i][j] = __builtin_amdgcn_mfma_f32_16x16x32_bf16(af[i], bf8[j], acc[i][j], 0, 0, 0);
    __syncthreads();
  }
#pragma unroll
  for (int j = 0; j < 4; j++) {
    const int colg = n0 + wn + j * 16 + l16;
    const float bb = bias[colg];
#pragma unroll
    for (int i = 0; i < 4; i++) {
      const int rowg = m0 + wm + i * 16 + q4 * 4;
#pragma unroll
      for (int r = 0; r < 4; r++)
        Out[(size_t)(rowg + r) * D + colg] = __float2bfloat16(acc[i][j][r] + bb);
    }
  }
}

// ---------------- Kernel 2: weighted column norms  ns[b,d] = sum_n w*psi^2 ----------------
__global__ __launch_bounds__(256) void norms_k(
    const __hip_bfloat16* __restrict__ Kb, const __hip_bfloat16* __restrict__ Vb,
    const float* __restrict__ wts, float* __restrict__ nsk, float* __restrict__ nsv) {
  const int b = blockIdx.y;
  const int r0 = blockIdx.x * 256;
  const int t = threadIdx.x;
  const int half = t >> 7, c2 = t & 127;  // c2: uint32 column index (cols 2c2, 2c2+1)
  const uint32_t* K32 = (const uint32_t*)Kb;
  const uint32_t* V32 = (const uint32_t*)Vb;
  float ak0 = 0, ak1 = 0, av0 = 0, av1 = 0;
  for (int i = 0; i < 128; i++) {
    const int row = r0 + i * 2 + half;
    const size_t rb = (size_t)b * NTOK + row;
    const float w = wts[rb];
    const uint32_t ku = K32[rb * 128 + c2];
    const uint32_t vu = V32[rb * 128 + c2];
    const float k0 = bflo(ku), k1 = bfhi(ku), v0 = bflo(vu), v1 = bfhi(vu);
    ak0 += w * k0 * k0; ak1 += w * k1 * k1;
    av0 += w * v0 * v0; av1 += w * v1 * v1;
  }
  atomicAdd(&nsk[b * D + c2 * 2], ak0);
  atomicAdd(&nsk[b * D + c2 * 2 + 1], ak1);
  atomicAdd(&nsv[b * D + c2 * 2], av0);
  atomicAdd(&nsv[b * D + c2 * 2 + 1], av1);
}

// ---------------- Kernel 3: rotary(Q); K: norm+rotary+*w; V: norm (in place) ----------------
__global__ __launch_bounds__(256) void pointwise(
    __hip_bfloat16* __restrict__ Qb, __hip_bfloat16* __restrict__ Kb,
    __hip_bfloat16* __restrict__ Vb, const float* __restrict__ coords,
    const float* __restrict__ wts, const float* __restrict__ lift,
    const float* __restrict__ nsk, const float* __restrict__ nsv) {
  const int t = threadIdx.x;
  const int j = t & 63, rloc = t >> 6;  // j: uint32 pair index (cols 2j,2j+1, partners +128)
  const size_t row = (size_t)blockIdx.x * 4 + rloc;
  const int b = (int)(row >> 13);
  const float cx = coords[row * 3 + 0];
  const float cy = coords[row * 3 + 1];
  const float cz = coords[row * 3 + 2];
  const int j0 = 2 * j, j1 = 2 * j + 1;
  const float p0 = cx * lift[j0 * 3 + 0] + cy * lift[j0 * 3 + 1] + cz * lift[j0 * 3 + 2];
  const float p1 = cx * lift[j1 * 3 + 0] + cy * lift[j1 * 3 + 1] + cz * lift[j1 * 3 + 2];
  float s0, c0, s1, c1;
  sincosf(p0, &s0, &c0);
  sincosf(p1, &s1, &c1);
  const float w = wts[row];
  uint32_t* Q32 = (uint32_t*)Qb;
  uint32_t* K32 = (uint32_t*)Kb;
  uint32_t* V32 = (uint32_t*)Vb;
  const size_t base = row * 128;
  // Q: rotary only
  {
    const uint32_t qlo = Q32[base + j], qhi = Q32[base + 64 + j];
    const float q1a = bflo(qlo), q1b = bfhi(qlo), q2a = bflo(qhi), q2b = bfhi(qhi);
    Q32[base + j]      = packbf(q1a * c0 - q2a * s0, q1b * c1 - q2b * s1);
    Q32[base + 64 + j] = packbf(q1a * s0 + q2a * c0, q1b * s1 + q2b * c1);
  }
  const int nb = b * D;
  // K: basis_norm -> rotary -> *w
  {
    const float ik0 = rsqrtf(nsk[nb + j0] + 1e-5f);
    const float ik1 = rsqrtf(nsk[nb + j1] + 1e-5f);
    const float ik2 = rsqrtf(nsk[nb + 128 + j0] + 1e-5f);
    const float ik3 = rsqrtf(nsk[nb + 128 + j1] + 1e-5f);
    const uint32_t klo = K32[base + j], khi = K32[base + 64 + j];
    const float k1a = bflo(klo) * ik0, k1b = bfhi(klo) * ik1;
    const float k2a = bflo(khi) * ik2, k2b = bfhi(khi) * ik3;
    K32[base + j]      = packbf((k1a * c0 - k2a * s0) * w, (k1b * c1 - k2b * s1) * w);
    K32[base + 64 + j] = packbf((k1a * s0 + k2a * c0) * w, (k1b * s1 + k2b * c1) * w);
  }
  // V: basis_norm only
  {
    const float iv0 = rsqrtf(nsv[nb + j0] + 1e-5f);
    const float iv1 = rsqrtf(nsv[nb + j1] + 1e-5f);
    const float iv2 = rsqrtf(nsv[nb + 128 + j0] + 1e-5f);
    const float iv3 = rsqrtf(nsv[nb + 128 + j1] + 1e-5f);
    const uint32_t vlo = V32[base + j], vhi = V32[base + 64 + j];
    V32[base + j]      = packbf(bflo(vlo) * iv0, bfhi(vlo) * iv1);
    V32[base + 64 + j] = packbf(bflo(vhi) * iv2, bfhi(vhi) * iv3);
  }
}

// ---------------- Kernel 4: KVt[b][e][d] = sum_n v[n][e]*kw[n][d]  (TN gemm, split-K) -------
__global__ __launch_bounds__(256, 2) void gemm_tn(
    const __hip_bfloat16* __restrict__ Vb, const __hip_bfloat16* __restrict__ Kwb,
    float* __restrict__ KVt) {
  __shared__ __align__(16) char sm[2 * 32 * 260];  // padded rows: 260B
  char* Asm = sm;
  char* Bsm = sm + 32 * 260;
  const int t = threadIdx.x, lane = t & 63, wid = t >> 6;
  const int wm = (wid & 1) * 64, wn = (wid >> 1) * 64;
  const int l16 = lane & 15, q4 = lane >> 4;
  const int b = blockIdx.z, chunk = blockIdx.y;
  const int e0 = (blockIdx.x & 1) * 128, d0 = (blockIdx.x >> 1) * 128;
  const uint32_t* V32 = (const uint32_t*)Vb;
  const uint32_t* K32 = (const uint32_t*)Kwb;
  floatx4 acc[4][4] = {};
  for (int nt = 0; nt < 1024; nt += 32) {
    const int nbase = chunk * 1024 + nt;
#pragma unroll
    for (int rep = 0; rep < 8; rep++) {
      const int flat = rep * 256 + t;
      const int nn = flat >> 6;
      const int e2 = flat & 63;
      const size_t src = ((size_t)b * NTOK + nbase + nn) * 128;
      *(uint32_t*)(Asm + nn * 260 + e2 * 4) = V32[src + (e0 >> 1) + e2];
      *(uint32_t*)(Bsm + nn * 260 + e2 * 4) = K32[src + (d0 >> 1) + e2];
    }
    __syncthreads();
    short8 af[4], bf8[4];
#pragma unroll
    for (int i = 0; i < 4; i++) {
#pragma unroll
      for (int jj = 0; jj < 8; jj++) {
        af[i][jj]  = *(const short*)(Asm + (q4 * 8 + jj) * 260 + (wm + i * 16 + l16) * 2);
        bf8[i][jj] = *(const short*)(Bsm + (q4 * 8 + jj) * 260 + (wn + i * 16 + l16) * 2);
      }
    }
#pragma unroll
    for (int i = 0; i < 4; i++)
#pragma unroll
      for (int j = 0; j < 4; j++)
        acc[i][j] = __builtin_amdgcn_mfma_f32_16x16x32_bf16(af[i], bf8[j], acc[i][j], 0, 0, 0);
    __syncthreads();
  }
#pragma unroll
  for (int i = 0; i < 4; i++) {
#pragma unroll
    for (int r = 0; r < 4; r++) {
      const int eg = e0 + wm + i * 16 + q4 * 4 + r;
#pragma unroll
      for (int j = 0; j < 4; j++) {
        const int dg = d0 + wn + j * 16 + l16;
        atomicAdd(&KVt[((size_t)b * D + eg) * D + dg], acc[i][j][r]);
      }
    }
  }
}

// ---------------- Kernel 5: P[b][f][d] = sum_e Wo[f][e] * KVt[b][e][d]  (bf16 out) ----------
__global__ __launch_bounds__(256) void make_p(const float* __restrict__ KVt,
                                              const float* __restrict__ Wo,
                                              __hip_bfloat16* __restrict__ P) {
  const int b = blockIdx.x >> 5;
  const int f0 = (blockIdx.x & 31) * 8;
  const int d = threadIdx.x;
  float acc[8] = {};
  for (int e = 0; e < 256; e++) {
    const float kv = KVt[((size_t)b * D + e) * D + d];
#pragma unroll
    for (int ff = 0; ff < 8; ff++)
      acc[ff] += Wo[(f0 + ff) * D + e] * kv;
  }
#pragma unroll
  for (int ff = 0; ff < 8; ff++)
    P[((size_t)b * D + f0 + ff) * D + d] = __float2bfloat16(acc[ff]);
}

// ---------------- Kernel 6: out = q_rot @ P^T + bo  (fp32 out to d_out) ---------------------
__global__ __launch_bounds__(256, 2) void gemm_out(
    const __hip_bfloat16* __restrict__ A, const __hip_bfloat16* __restrict__ Pm,
    const float* __restrict__ bo, float* __restrict__ Og) {
  __shared__ __align__(16) char As[8192];
  __shared__ __align__(16) char Bs[8192];
  const int t = threadIdx.x, lane = t & 63, wid = t >> 6;
  const int wm = (wid & 1) * 64, wn = (wid >> 1) * 64;
  const int l16 = lane & 15, q4 = lane >> 4;
  const int m0 = blockIdx.x * 128, n0 = blockIdx.y * 128;
  const int b = m0 >> 13;
  const __hip_bfloat16* W = Pm + ((size_t)b << 16);
  floatx4 acc[4][4] = {};
  const int srow = wid * 16 + (lane >> 2);
  const int skoff = (lane & 3) * 8;
  const __hip_bfloat16* gA = A + (size_t)(m0 + srow) * D + skoff;
  const __hip_bfloat16* gB = W + (size_t)(n0 + srow) * D + skoff;
  char* lA = As + srow * 64 + skoff * 2;
  char* lB = Bs + srow * 64 + skoff * 2;
  for (int kt = 0; kt < 256; kt += 32) {
    gl_lds16(gA + kt, lA);
    gl_lds16(gA + kt + 64 * D, lA + 4096);
    gl_lds16(gB + kt, lB);
    gl_lds16(gB + kt + 64 * D, lB + 4096);
    __syncthreads();
    short8 af[4], bf8[4];
#pragma unroll
    for (int i = 0; i < 4; i++) {
      af[i]  = *(const short8*)(As + (wm + i * 16 + l16) * 64 + q4 * 16);
      bf8[i] = *(const short8*)(Bs + (wn + i * 16 + l16) * 64 + q4 * 16);
    }
#pragma unroll
    for (int i = 0; i < 4; i++)
#pragma unroll
      for (int j = 0; j < 4; j++)
        acc[i][j] = __builtin_amdgcn_mfma_f32_16x16x32_bf16(af[i], bf8[j], acc[i][j], 0, 0, 0);
    __syncthreads();
  }
#pragma unroll
  for (int j = 0; j < 4; j++) {
    const int colg = n0 + wn + j * 16 + l16;
    const float bb = bo[colg];
#pragma unroll
    for (int i = 0; i < 4; i++) {
      const int rowg = m0 + wm + i * 16 + q4 * 4;
#pragma unroll
      for (int r = 0; r < 4; r++)
        Og[(size_t)(rowg + r) * D + colg] = acc[i][j][r] + bb;
    }
  }
}

extern "C" void kernel_launch(void* const* d_in, const int* in_sizes, int n_in,
                              void* d_out, int out_size, void* d_ws, size_t ws_size,
                              hipStream_t stream) {
  const float* phi    = (const float*)d_in[0];
  const float* coords = (const float*)d_in[1];
  const float* wts    = (const float*)d_in[2];
  const float* Wq     = (const float*)d_in[3];
  const float* bq     = (const float*)d_in[4];
  const float* Wk     = (const float*)d_in[5];
  const float* bk     = (const float*)d_in[6];
  const float* Wv     = (const float*)d_in[7];
  const float* bv     = (const float*)d_in[8];
  const float* Wo     = (const float*)d_in[9];
  const float* bo     = (const float*)d_in[10];
  const float* lift   = (const float*)d_in[11];

  char* ws = (char*)d_ws;
  // bf16 region written by convert: [phi16 | Wq16 | Wk16 | Wv16]
  __hip_bfloat16* phi16 = (__hip_bfloat16*)ws;                 // 16 MiB
  __hip_bfloat16* Wq16  = (__hip_bfloat16*)(ws + 16777216);
  __hip_bfloat16* Wk16  = (__hip_bfloat16*)(ws + 16908288);
  __hip_bfloat16* Wv16  = (__hip_bfloat16*)(ws + 17039360);
  const size_t QOFF = 17170432;
  const size_t SZ = (size_t)MTOT * D * 2;  // 16 MiB per bf16 buffer
  __hip_bfloat16* Qb = (__hip_bfloat16*)(ws + QOFF);
  __hip_bfloat16* Kb = (__hip_bfloat16*)(ws + QOFF + SZ);
  __hip_bfloat16* Vb = (__hip_bfloat16*)(ws + QOFF + 2 * SZ);
  const size_t NOFF = QOFF + 3 * SZ;       // 67502080
  float* nsk = (float*)(ws + NOFF);
  float* nsv = (float*)(ws + NOFF + 4096);
  float* KVt = (float*)(ws + NOFF + 8192);
  __hip_bfloat16* P = (__hip_bfloat16*)(ws + NOFF + 8192 + (size_t)4 * D * D * 4);

  // zero norm accumulators + KVt (atomicAdd targets)
  hipMemsetAsync(ws + NOFF, 0, 8192 + (size_t)4 * D * D * 4, stream);

  // fp32 -> bf16: phi + Wq + Wk + Wv = 8585216 elems = 4292608 pairs = 16768 blocks
  convert<<<16768, 256, 0, stream>>>(phi, Wq, Wk, Wv, (uint32_t*)ws);
  gemm_qkv<<<dim3(256, 6), 256, 0, stream>>>(phi16, Wq16, bq, Wk16, bk, Wv16, bv, Qb, Kb, Vb);
  norms_k<<<dim3(32, 4), 256, 0, stream>>>(Kb, Vb, wts, nsk, nsv);
  pointwise<<<8192, 256, 0, stream>>>(Qb, Kb, Vb, coords, wts, lift, nsk, nsv);
  gemm_tn<<<dim3(4, 8, 4), 256, 0, stream>>>(Vb, Kb, KVt);
  make_p<<<128, 256, 0, stream>>>(KVt, Wo, P);
  gemm_out<<<dim3(256, 2), 256, 0, stream>>>(Qb, P, bo, (float*)d_out);
}

// Round 3
// 225.454 us; speedup vs baseline: 1.0464x; 1.0464x over previous
//
#include <hip/hip_runtime.h>
#include <hip/hip_bf16.h>
#include <stdint.h>

#define DEV __device__ __forceinline__

typedef short short8 __attribute__((ext_vector_type(8)));
typedef float floatx4 __attribute__((ext_vector_type(4)));

constexpr int D = 256;
constexpr int NTOK = 8192;
constexpr int MTOT = 4 * NTOK;  // 32768 rows total

DEV void gl_lds16(const void* g, void* l) {
  __builtin_amdgcn_global_load_lds(
      (const __attribute__((address_space(1))) void*)g,
      (__attribute__((address_space(3))) void*)l, 16, 0, 0);
}

DEV float bflo(uint32_t u) { return __uint_as_float(u << 16); }
DEV float bfhi(uint32_t u) { return __uint_as_float(u & 0xffff0000u); }
DEV uint32_t packbf(float a, float b) {
  uint16_t xa = __builtin_bit_cast(uint16_t, __float2bfloat16(a));
  uint16_t xb = __builtin_bit_cast(uint16_t, __float2bfloat16(b));
  return (uint32_t)xa | ((uint32_t)xb << 16);
}

// ---------------- Kernel 0: fp32 -> bf16 conversion of phi, Wq, Wk, Wv ----------------
constexpr int PHI_E = MTOT * D;          // 8388608
constexpr int W_E = D * D;               // 65536
__global__ __launch_bounds__(256) void convert(
    const float* __restrict__ phi, const float* __restrict__ Wq,
    const float* __restrict__ Wk, const float* __restrict__ Wv,
    uint32_t* __restrict__ dst) {
  const int idx2 = blockIdx.x * 256 + threadIdx.x;  // pair index
  const int e0 = idx2 * 2;
  float2 v;
  if (e0 < PHI_E) {
    v = ((const float2*)phi)[idx2];
  } else {
    int r = e0 - PHI_E;
    if (r < W_E) v = ((const float2*)Wq)[r >> 1];
    else if (r < 2 * W_E) v = ((const float2*)Wk)[(r - W_E) >> 1];
    else v = ((const float2*)Wv)[(r - 2 * W_E) >> 1];
  }
  dst[idx2] = packbf(v.x, v.y);
}

// ---------------- Kernel 1: fused QKV GEMM, 128x256 tile per block --------------------------
// blockIdx.y = mat (0=Q,1=K,2=V). Fuses: bias add; Q-rotary (fp32); w-weighted column norm
// partials for K/V (atomicAdd into nsk/nsv). V stored RAW (normalization folded into make_p).
__global__ __launch_bounds__(256, 2) void gemm_qkv(
    const __hip_bfloat16* __restrict__ phi,
    const __hip_bfloat16* __restrict__ W16,   // [Wq|Wk|Wv] bf16, row-major D x D each
    const float* __restrict__ bq, const float* __restrict__ bk, const float* __restrict__ bv,
    const float* __restrict__ coords, const float* __restrict__ wts,
    const float* __restrict__ lift,
    __hip_bfloat16* __restrict__ Qb, __hip_bfloat16* __restrict__ Kb,
    __hip_bfloat16* __restrict__ Vb, float* __restrict__ nsk, float* __restrict__ nsv) {
  __shared__ __align__(16) char As[8192];    // 128 rows x 64B (32 bf16 k-slice)
  __shared__ __align__(16) char Bs[16384];   // 256 rows x 64B
  const int t = threadIdx.x, lane = t & 63, wid = t >> 6;
  const int wm = (wid & 1) * 64, wn = (wid >> 1) * 64;
  const int l16 = lane & 15, q4 = lane >> 4;
  const int m0 = blockIdx.x * 128;
  const int mat = blockIdx.y;
  const __hip_bfloat16* W = W16 + (size_t)mat * W_E;
  const float* bias = (mat == 0) ? bq : (mat == 1) ? bk : bv;
  __hip_bfloat16* Out = (mat == 0) ? Qb : (mat == 1) ? Kb : Vb;

  floatx4 acc[4][8] = {};

  const int srow = wid * 16 + (lane >> 2);   // 0..63
  const int skoff = (lane & 3) * 8;
  const __hip_bfloat16* gA = phi + (size_t)(m0 + srow) * D + skoff;
  const __hip_bfloat16* gB = W + (size_t)srow * D + skoff;
  char* lA = As + srow * 64 + skoff * 2;
  char* lB = Bs + srow * 64 + skoff * 2;

  for (int kt = 0; kt < 256; kt += 32) {
    gl_lds16(gA + kt, lA);
    gl_lds16(gA + kt + 64 * D, lA + 4096);
    gl_lds16(gB + kt, lB);
    gl_lds16(gB + kt + 64 * D, lB + 4096);
    gl_lds16(gB + kt + 128 * D, lB + 8192);
    gl_lds16(gB + kt + 192 * D, lB + 12288);
    __syncthreads();
    short8 af[4], bf8[8];
#pragma unroll
    for (int i = 0; i < 4; i++)
      af[i] = *(const short8*)(As + (wm + i * 16 + l16) * 64 + q4 * 16);
#pragma unroll
    for (int j = 0; j < 8; j++) {
      const int col = wn + (j & 3) * 16 + (j >> 2) * 128 + l16;
      bf8[j] = *(const short8*)(Bs + col * 64 + q4 * 16);
    }
#pragma unroll
    for (int i = 0; i < 4; i++)
#pragma unroll
      for (int j = 0; j < 8; j++)
        acc[i][j] = __builtin_amdgcn_mfma_f32_16x16x32_bf16(af[i], bf8[j], acc[i][j], 0, 0, 0);
    __syncthreads();
  }

  // hoisted per-lane column constants
  float bcol[8];
#pragma unroll
  for (int j = 0; j < 8; j++)
    bcol[j] = bias[wn + (j & 3) * 16 + (j >> 2) * 128 + l16];

  if (mat == 0) {
    // Q: add bias, apply rotary in fp32, store bf16
    float lx[4], ly[4], lz[4];
#pragma unroll
    for (int jj = 0; jj < 4; jj++) {
      const int c = wn + jj * 16 + l16;  // pair index 0..127
      lx[jj] = lift[c * 3 + 0]; ly[jj] = lift[c * 3 + 1]; lz[jj] = lift[c * 3 + 2];
    }
#pragma unroll
    for (int i = 0; i < 4; i++) {
#pragma unroll
      for (int r = 0; r < 4; r++) {
        const int row = m0 + wm + i * 16 + q4 * 4 + r;
        const float cx = coords[row * 3 + 0];
        const float cy = coords[row * 3 + 1];
        const float cz = coords[row * 3 + 2];
#pragma unroll
        for (int jj = 0; jj < 4; jj++) {
          const int c = wn + jj * 16 + l16;
          const float p = cx * lx[jj] + cy * ly[jj] + cz * lz[jj];
          float s, cs;
          __sincosf(p, &s, &cs);
          const float f1 = acc[i][jj][r] + bcol[jj];
          const float f2 = acc[i][jj + 4][r] + bcol[jj + 4];
          Out[(size_t)row * D + c]       = __float2bfloat16(f1 * cs - f2 * s);
          Out[(size_t)row * D + c + 128] = __float2bfloat16(f1 * s + f2 * cs);
        }
      }
    }
  } else {
    // K/V: add bias, store raw psi bf16, accumulate w-weighted column norms
    const int b = m0 >> 13;
    float* ns = (mat == 1) ? nsk : nsv;
    float colsum[8] = {};
#pragma unroll
    for (int i = 0; i < 4; i++) {
#pragma unroll
      for (int r = 0; r < 4; r++) {
        const int row = m0 + wm + i * 16 + q4 * 4 + r;
        const float w = wts[row];
#pragma unroll
        for (int j = 0; j < 8; j++) {
          const int col = wn + (j & 3) * 16 + (j >> 2) * 128 + l16;
          const float psi = acc[i][j][r] + bcol[j];
          Out[(size_t)row * D + col] = __float2bfloat16(psi);
          colsum[j] += w * psi * psi;
        }
      }
    }
#pragma unroll
    for (int j = 0; j < 8; j++) {
      float s = colsum[j];
      s += __shfl_xor(s, 16);
      s += __shfl_xor(s, 32);
      if (q4 == 0) {
        const int col = wn + (j & 3) * 16 + (j >> 2) * 128 + l16;
        atomicAdd(&ns[b * D + col], s);
      }
    }
  }
}

// ---------------- Kernel 2: K pointwise: basis_norm -> rotary -> *w (in place) --------------
__global__ __launch_bounds__(256) void pointwise_k(
    __hip_bfloat16* __restrict__ Kb, const float* __restrict__ coords,
    const float* __restrict__ wts, const float* __restrict__ lift,
    const float* __restrict__ nsk) {
  const int t = threadIdx.x;
  const int j = t & 63, rloc = t >> 6;  // j: uint32 pair idx (cols 2j,2j+1, partners +128)
  const size_t row = (size_t)blockIdx.x * 4 + rloc;
  const int b = (int)(row >> 13);
  const float cx = coords[row * 3 + 0];
  const float cy = coords[row * 3 + 1];
  const float cz = coords[row * 3 + 2];
  const int j0 = 2 * j, j1 = 2 * j + 1;
  const float p0 = cx * lift[j0 * 3 + 0] + cy * lift[j0 * 3 + 1] + cz * lift[j0 * 3 + 2];
  const float p1 = cx * lift[j1 * 3 + 0] + cy * lift[j1 * 3 + 1] + cz * lift[j1 * 3 + 2];
  float s0, c0, s1, c1;
  __sincosf(p0, &s0, &c0);
  __sincosf(p1, &s1, &c1);
  const float w = wts[row];
  uint32_t* K32 = (uint32_t*)Kb;
  const size_t base = row * 128;
  const int nb = b * D;
  const float ik0 = rsqrtf(nsk[nb + j0] + 1e-5f);
  const float ik1 = rsqrtf(nsk[nb + j1] + 1e-5f);
  const float ik2 = rsqrtf(nsk[nb + 128 + j0] + 1e-5f);
  const float ik3 = rsqrtf(nsk[nb + 128 + j1] + 1e-5f);
  const uint32_t klo = K32[base + j], khi = K32[base + 64 + j];
  const float k1a = bflo(klo) * ik0, k1b = bfhi(klo) * ik1;
  const float k2a = bflo(khi) * ik2, k2b = bfhi(khi) * ik3;
  K32[base + j]      = packbf((k1a * c0 - k2a * s0) * w, (k1b * c1 - k2b * s1) * w);
  K32[base + 64 + j] = packbf((k1a * s0 + k2a * c0) * w, (k1b * s1 + k2b * c1) * w);
}

// ---------------- Kernel 3: KVt[b][e][d] = sum_n vraw[n][e]*kw[n][d]  (TN gemm, split-K) ----
__global__ __launch_bounds__(256, 2) void gemm_tn(
    const __hip_bfloat16* __restrict__ Vb, const __hip_bfloat16* __restrict__ Kwb,
    float* __restrict__ KVt) {
  __shared__ __align__(16) char sm[2 * 32 * 260];  // padded rows: 260B
  char* Asm = sm;
  char* Bsm = sm + 32 * 260;
  const int t = threadIdx.x, lane = t & 63, wid = t >> 6;
  const int wm = (wid & 1) * 64, wn = (wid >> 1) * 64;
  const int l16 = lane & 15, q4 = lane >> 4;
  const int chunk = blockIdx.x;            // 16 chunks of 512 tokens (fastest -> XCD locality)
  const int ed = blockIdx.y, b = blockIdx.z;
  const int e0 = (ed & 1) * 128, d0 = (ed >> 1) * 128;
  const uint32_t* V32 = (const uint32_t*)Vb;
  const uint32_t* K32 = (const uint32_t*)Kwb;
  floatx4 acc[4][4] = {};
  for (int nt = 0; nt < 512; nt += 32) {
    const int nbase = chunk * 512 + nt;
#pragma unroll
    for (int rep = 0; rep < 8; rep++) {
      const int flat = rep * 256 + t;
      const int nn = flat >> 6;
      const int e2 = flat & 63;
      const size_t src = ((size_t)b * NTOK + nbase + nn) * 128;
      *(uint32_t*)(Asm + nn * 260 + e2 * 4) = V32[src + (e0 >> 1) + e2];
      *(uint32_t*)(Bsm + nn * 260 + e2 * 4) = K32[src + (d0 >> 1) + e2];
    }
    __syncthreads();
    short8 af[4], bf8[4];
#pragma unroll
    for (int i = 0; i < 4; i++) {
#pragma unroll
      for (int jj = 0; jj < 8; jj++) {
        af[i][jj]  = *(const short*)(Asm + (q4 * 8 + jj) * 260 + (wm + i * 16 + l16) * 2);
        bf8[i][jj] = *(const short*)(Bsm + (q4 * 8 + jj) * 260 + (wn + i * 16 + l16) * 2);
      }
    }
#pragma unroll
    for (int i = 0; i < 4; i++)
#pragma unroll
      for (int j = 0; j < 4; j++)
        acc[i][j] = __builtin_amdgcn_mfma_f32_16x16x32_bf16(af[i], bf8[j], acc[i][j], 0, 0, 0);
    __syncthreads();
  }
#pragma unroll
  for (int i = 0; i < 4; i++) {
#pragma unroll
    for (int r = 0; r < 4; r++) {
      const int eg = e0 + wm + i * 16 + q4 * 4 + r;
#pragma unroll
      for (int j = 0; j < 4; j++) {
        const int dg = d0 + wn + j * 16 + l16;
        atomicAdd(&KVt[((size_t)b * D + eg) * D + dg], acc[i][j][r]);
      }
    }
  }
}

// ---------------- Kernel 4: P[b][f][d] = sum_e Wo[f][e]*sv[b][e]*KVt[b][e][d] ---------------
__global__ __launch_bounds__(256) void make_p(const float* __restrict__ KVt,
                                              const float* __restrict__ nsv,
                                              const float* __restrict__ Wo,
                                              __hip_bfloat16* __restrict__ P) {
  const int b = blockIdx.x >> 5;
  const int f0 = (blockIdx.x & 31) * 8;
  const int d = threadIdx.x;
  float acc[8] = {};
  for (int e = 0; e < 256; e++) {
    const float sv = rsqrtf(nsv[b * D + e] + 1e-5f);  // V norm folded here
    const float kv = KVt[((size_t)b * D + e) * D + d] * sv;
#pragma unroll
    for (int ff = 0; ff < 8; ff++)
      acc[ff] += Wo[(f0 + ff) * D + e] * kv;
  }
#pragma unroll
  for (int ff = 0; ff < 8; ff++)
    P[((size_t)b * D + f0 + ff) * D + d] = __float2bfloat16(acc[ff]);
}

// ---------------- Kernel 5: out = q_rot @ P^T + bo  (fp32 out to d_out) ---------------------
__global__ __launch_bounds__(256, 2) void gemm_out(
    const __hip_bfloat16* __restrict__ A, const __hip_bfloat16* __restrict__ Pm,
    const float* __restrict__ bo, float* __restrict__ Og) {
  __shared__ __align__(16) char As[8192];
  __shared__ __align__(16) char Bs[8192];
  const int t = threadIdx.x, lane = t & 63, wid = t >> 6;
  const int wm = (wid & 1) * 64, wn = (wid >> 1) * 64;
  const int l16 = lane & 15, q4 = lane >> 4;
  const int m0 = blockIdx.x * 128, n0 = blockIdx.y * 128;
  const int b = m0 >> 13;
  const __hip_bfloat16* W = Pm + ((size_t)b << 16);
  floatx4 acc[4][4] = {};
  const int srow = wid * 16 + (lane >> 2);
  const int skoff = (lane & 3) * 8;
  const __hip_bfloat16* gA = A + (size_t)(m0 + srow) * D + skoff;
  const __hip_bfloat16* gB = W + (size_t)(n0 + srow) * D + skoff;
  char* lA = As + srow * 64 + skoff * 2;
  char* lB = Bs + srow * 64 + skoff * 2;
  for (int kt = 0; kt < 256; kt += 32) {
    gl_lds16(gA + kt, lA);
    gl_lds16(gA + kt + 64 * D, lA + 4096);
    gl_lds16(gB + kt, lB);
    gl_lds16(gB + kt + 64 * D, lB + 4096);
    __syncthreads();
    short8 af[4], bf8[4];
#pragma unroll
    for (int i = 0; i < 4; i++) {
      af[i]  = *(const short8*)(As + (wm + i * 16 + l16) * 64 + q4 * 16);
      bf8[i] = *(const short8*)(Bs + (wn + i * 16 + l16) * 64 + q4 * 16);
    }
#pragma unroll
    for (int i = 0; i < 4; i++)
#pragma unroll
      for (int j = 0; j < 4; j++)
        acc[i][j] = __builtin_amdgcn_mfma_f32_16x16x32_bf16(af[i], bf8[j], acc[i][j], 0, 0, 0);
    __syncthreads();
  }
#pragma unroll
  for (int j = 0; j < 4; j++) {
    const int colg = n0 + wn + j * 16 + l16;
    const float bb = bo[colg];
#pragma unroll
    for (int i = 0; i < 4; i++) {
      const int rowg = m0 + wm + i * 16 + q4 * 4;
#pragma unroll
      for (int r = 0; r < 4; r++)
        Og[(size_t)(rowg + r) * D + colg] = acc[i][j][r] + bb;
    }
  }
}

extern "C" void kernel_launch(void* const* d_in, const int* in_sizes, int n_in,
                              void* d_out, int out_size, void* d_ws, size_t ws_size,
                              hipStream_t stream) {
  const float* phi    = (const float*)d_in[0];
  const float* coords = (const float*)d_in[1];
  const float* wts    = (const float*)d_in[2];
  const float* Wq     = (const float*)d_in[3];
  const float* bq     = (const float*)d_in[4];
  const float* Wk     = (const float*)d_in[5];
  const float* bk     = (const float*)d_in[6];
  const float* Wv     = (const float*)d_in[7];
  const float* bv     = (const float*)d_in[8];
  const float* Wo     = (const float*)d_in[9];
  const float* bo     = (const float*)d_in[10];
  const float* lift   = (const float*)d_in[11];

  char* ws = (char*)d_ws;
  // bf16 region written by convert: [phi16 | Wq16 | Wk16 | Wv16]
  __hip_bfloat16* phi16 = (__hip_bfloat16*)ws;            // 16 MiB
  __hip_bfloat16* W16   = (__hip_bfloat16*)(ws + 16777216);
  const size_t QOFF = 17170432;
  const size_t SZ = (size_t)MTOT * D * 2;  // 16 MiB per bf16 buffer
  __hip_bfloat16* Qb = (__hip_bfloat16*)(ws + QOFF);
  __hip_bfloat16* Kb = (__hip_bfloat16*)(ws + QOFF + SZ);
  __hip_bfloat16* Vb = (__hip_bfloat16*)(ws + QOFF + 2 * SZ);
  const size_t NOFF = QOFF + 3 * SZ;       // 67502080
  float* nsk = (float*)(ws + NOFF);
  float* nsv = (float*)(ws + NOFF + 4096);
  float* KVt = (float*)(ws + NOFF + 8192);
  __hip_bfloat16* P = (__hip_bfloat16*)(ws + NOFF + 8192 + (size_t)4 * D * D * 4);

  // zero norm accumulators + KVt (atomicAdd targets)
  hipMemsetAsync(ws + NOFF, 0, 8192 + (size_t)4 * D * D * 4, stream);

  // fp32 -> bf16: phi + Wq + Wk + Wv = 8585216 elems = 4292608 pairs = 16768 blocks
  convert<<<16768, 256, 0, stream>>>(phi, Wq, Wk, Wv, (uint32_t*)ws);
  gemm_qkv<<<dim3(256, 3), 256, 0, stream>>>(phi16, W16, bq, bk, bv, coords, wts, lift,
                                             Qb, Kb, Vb, nsk, nsv);
  pointwise_k<<<8192, 256, 0, stream>>>(Kb, coords, wts, lift, nsk);
  gemm_tn<<<dim3(16, 4, 4), 256, 0, stream>>>(Vb, Kb, KVt);
  make_p<<<128, 256, 0, stream>>>(KVt, nsv, Wo, P);
  gemm_out<<<dim3(256, 2), 256, 0, stream>>>(Qb, P, bo, (float*)d_out);
}

// Round 4
// 205.124 us; speedup vs baseline: 1.1501x; 1.0991x over previous
//
#include <hip/hip_runtime.h>
#include <hip/hip_bf16.h>
#include <stdint.h>

#define DEV __device__ __forceinline__

typedef short short8 __attribute__((ext_vector_type(8)));
typedef float floatx4 __attribute__((ext_vector_type(4)));

constexpr int D = 256;
constexpr int NTOK = 8192;
constexpr int MTOT = 4 * NTOK;  // 32768 rows total

DEV void gl_lds16(const void* g, void* l) {
  __builtin_amdgcn_global_load_lds(
      (const __attribute__((address_space(1))) void*)g,
      (__attribute__((address_space(3))) void*)l, 16, 0, 0);
}

DEV float bflo(uint32_t u) { return __uint_as_float(u << 16); }
DEV float bfhi(uint32_t u) { return __uint_as_float(u & 0xffff0000u); }
DEV uint32_t packbf(float a, float b) {
  uint16_t xa = __builtin_bit_cast(uint16_t, __float2bfloat16(a));
  uint16_t xb = __builtin_bit_cast(uint16_t, __float2bfloat16(b));
  return (uint32_t)xa | ((uint32_t)xb << 16);
}

// ---------------- Kernel 0: fp32 -> bf16 conversion of phi, Wq, Wk, Wv ----------------
constexpr int PHI_E = MTOT * D;          // 8388608
constexpr int W_E = D * D;               // 65536
__global__ __launch_bounds__(256) void convert(
    const float* __restrict__ phi, const float* __restrict__ Wq,
    const float* __restrict__ Wk, const float* __restrict__ Wv,
    uint32_t* __restrict__ dst) {
  const int idx2 = blockIdx.x * 256 + threadIdx.x;  // pair index
  const int e0 = idx2 * 2;
  float2 v;
  if (e0 < PHI_E) {
    v = ((const float2*)phi)[idx2];
  } else {
    int r = e0 - PHI_E;
    if (r < W_E) v = ((const float2*)Wq)[r >> 1];
    else if (r < 2 * W_E) v = ((const float2*)Wk)[(r - W_E) >> 1];
    else v = ((const float2*)Wv)[(r - 2 * W_E) >> 1];
  }
  dst[idx2] = packbf(v.x, v.y);
}

// ---------------- Kernel 1: fused QKV GEMM, 128x256 tile per block --------------------------
// blockIdx.y = mat (0=Q,1=K,2=V). Fuses: bias add; Q-rotary (fp32); w-weighted column norm
// partials for K/V (atomicAdd into nsk/nsv). K/V stored RAW psi.
__global__ __launch_bounds__(256, 2) void gemm_qkv(
    const __hip_bfloat16* __restrict__ phi,
    const __hip_bfloat16* __restrict__ W16,   // [Wq|Wk|Wv] bf16, row-major D x D each
    const float* __restrict__ bq, const float* __restrict__ bk, const float* __restrict__ bv,
    const float* __restrict__ coords, const float* __restrict__ wts,
    const float* __restrict__ lift,
    __hip_bfloat16* __restrict__ Qb, __hip_bfloat16* __restrict__ Kb,
    __hip_bfloat16* __restrict__ Vb, float* __restrict__ nsk, float* __restrict__ nsv) {
  __shared__ __align__(16) char As[8192];    // 128 rows x 64B (32 bf16 k-slice)
  __shared__ __align__(16) char Bs[16384];   // 256 rows x 64B
  const int t = threadIdx.x, lane = t & 63, wid = t >> 6;
  const int wm = (wid & 1) * 64, wn = (wid >> 1) * 64;
  const int l16 = lane & 15, q4 = lane >> 4;
  const int m0 = blockIdx.x * 128;
  const int mat = blockIdx.y;
  const __hip_bfloat16* W = W16 + (size_t)mat * W_E;
  const float* bias = (mat == 0) ? bq : (mat == 1) ? bk : bv;
  __hip_bfloat16* Out = (mat == 0) ? Qb : (mat == 1) ? Kb : Vb;

  floatx4 acc[4][8] = {};

  const int srow = wid * 16 + (lane >> 2);   // 0..63
  const int skoff = (lane & 3) * 8;
  const __hip_bfloat16* gA = phi + (size_t)(m0 + srow) * D + skoff;
  const __hip_bfloat16* gB = W + (size_t)srow * D + skoff;
  char* lA = As + srow * 64 + skoff * 2;
  char* lB = Bs + srow * 64 + skoff * 2;

  for (int kt = 0; kt < 256; kt += 32) {
    gl_lds16(gA + kt, lA);
    gl_lds16(gA + kt + 64 * D, lA + 4096);
    gl_lds16(gB + kt, lB);
    gl_lds16(gB + kt + 64 * D, lB + 4096);
    gl_lds16(gB + kt + 128 * D, lB + 8192);
    gl_lds16(gB + kt + 192 * D, lB + 12288);
    __syncthreads();
    short8 af[4], bf8[8];
#pragma unroll
    for (int i = 0; i < 4; i++)
      af[i] = *(const short8*)(As + (wm + i * 16 + l16) * 64 + q4 * 16);
#pragma unroll
    for (int j = 0; j < 8; j++) {
      const int col = wn + (j & 3) * 16 + (j >> 2) * 128 + l16;
      bf8[j] = *(const short8*)(Bs + col * 64 + q4 * 16);
    }
#pragma unroll
    for (int i = 0; i < 4; i++)
#pragma unroll
      for (int j = 0; j < 8; j++)
        acc[i][j] = __builtin_amdgcn_mfma_f32_16x16x32_bf16(af[i], bf8[j], acc[i][j], 0, 0, 0);
    __syncthreads();
  }

  float bcol[8];
#pragma unroll
  for (int j = 0; j < 8; j++)
    bcol[j] = bias[wn + (j & 3) * 16 + (j >> 2) * 128 + l16];

  if (mat == 0) {
    // Q: add bias, apply rotary in fp32, store bf16
    float lx[4], ly[4], lz[4];
#pragma unroll
    for (int jj = 0; jj < 4; jj++) {
      const int c = wn + jj * 16 + l16;  // pair index 0..127
      lx[jj] = lift[c * 3 + 0]; ly[jj] = lift[c * 3 + 1]; lz[jj] = lift[c * 3 + 2];
    }
#pragma unroll
    for (int i = 0; i < 4; i++) {
#pragma unroll
      for (int r = 0; r < 4; r++) {
        const int row = m0 + wm + i * 16 + q4 * 4 + r;
        const float cx = coords[row * 3 + 0];
        const float cy = coords[row * 3 + 1];
        const float cz = coords[row * 3 + 2];
#pragma unroll
        for (int jj = 0; jj < 4; jj++) {
          const int c = wn + jj * 16 + l16;
          const float p = cx * lx[jj] + cy * ly[jj] + cz * lz[jj];
          float s, cs;
          __sincosf(p, &s, &cs);
          const float f1 = acc[i][jj][r] + bcol[jj];
          const float f2 = acc[i][jj + 4][r] + bcol[jj + 4];
          Out[(size_t)row * D + c]       = __float2bfloat16(f1 * cs - f2 * s);
          Out[(size_t)row * D + c + 128] = __float2bfloat16(f1 * s + f2 * cs);
        }
      }
    }
  } else {
    // K/V: add bias, store raw psi bf16, accumulate w-weighted column norms
    const int b = m0 >> 13;
    float* ns = (mat == 1) ? nsk : nsv;
    float colsum[8] = {};
#pragma unroll
    for (int i = 0; i < 4; i++) {
#pragma unroll
      for (int r = 0; r < 4; r++) {
        const int row = m0 + wm + i * 16 + q4 * 4 + r;
        const float w = wts[row];
#pragma unroll
        for (int j = 0; j < 8; j++) {
          const int col = wn + (j & 3) * 16 + (j >> 2) * 128 + l16;
          const float psi = acc[i][j][r] + bcol[j];
          Out[(size_t)row * D + col] = __float2bfloat16(psi);
          colsum[j] += w * psi * psi;
        }
      }
    }
#pragma unroll
    for (int j = 0; j < 8; j++) {
      float s = colsum[j];
      s += __shfl_xor(s, 16);
      s += __shfl_xor(s, 32);
      if (q4 == 0) {
        const int col = wn + (j & 3) * 16 + (j >> 2) * 128 + l16;
        atomicAdd(&ns[b * D + col], s);
      }
    }
  }
}

// ---------------- Kernel 2: K pointwise: basis_norm -> rotary -> *w (in place) --------------
__global__ __launch_bounds__(256) void pointwise_k(
    __hip_bfloat16* __restrict__ Kb, const float* __restrict__ coords,
    const float* __restrict__ wts, const float* __restrict__ lift,
    const float* __restrict__ nsk) {
  const int t = threadIdx.x;
  const int j = t & 63, rloc = t >> 6;
  const size_t row = (size_t)blockIdx.x * 4 + rloc;
  const int b = (int)(row >> 13);
  const float cx = coords[row * 3 + 0];
  const float cy = coords[row * 3 + 1];
  const float cz = coords[row * 3 + 2];
  const int j0 = 2 * j, j1 = 2 * j + 1;
  const float p0 = cx * lift[j0 * 3 + 0] + cy * lift[j0 * 3 + 1] + cz * lift[j0 * 3 + 2];
  const float p1 = cx * lift[j1 * 3 + 0] + cy * lift[j1 * 3 + 1] + cz * lift[j1 * 3 + 2];
  float s0, c0, s1, c1;
  __sincosf(p0, &s0, &c0);
  __sincosf(p1, &s1, &c1);
  const float w = wts[row];
  uint32_t* K32 = (uint32_t*)Kb;
  const size_t base = row * 128;
  const int nb = b * D;
  const float ik0 = rsqrtf(nsk[nb + j0] + 1e-5f);
  const float ik1 = rsqrtf(nsk[nb + j1] + 1e-5f);
  const float ik2 = rsqrtf(nsk[nb + 128 + j0] + 1e-5f);
  const float ik3 = rsqrtf(nsk[nb + 128 + j1] + 1e-5f);
  const uint32_t klo = K32[base + j], khi = K32[base + 64 + j];
  const float k1a = bflo(klo) * ik0, k1b = bfhi(klo) * ik1;
  const float k2a = bflo(khi) * ik2, k2b = bfhi(khi) * ik3;
  K32[base + j]      = packbf((k1a * c0 - k2a * s0) * w, (k1b * c1 - k2b * s1) * w);
  K32[base + 64 + j] = packbf((k1a * s0 + k2a * c0) * w, (k1b * s1 + k2b * c1) * w);
}

// ---------------- Kernel 3: wosv[b][f][e] = bf16( Wo[f][e] * rsqrt(nsv[b][e]+eps) ) ---------
__global__ __launch_bounds__(256) void make_wosv(
    const float* __restrict__ Wo, const float* __restrict__ nsv,
    uint32_t* __restrict__ wosv) {
  const int b = blockIdx.x >> 7;           // 4 b's
  const int f = (blockIdx.x & 127) * 2 + (threadIdx.x >> 7);
  const int e2 = threadIdx.x & 127;        // float2 index
  const float2 wo = ((const float2*)(Wo + (size_t)f * D))[e2];
  const float2 nv = ((const float2*)(nsv + b * D))[e2];
  const float a = wo.x * rsqrtf(nv.x + 1e-5f);
  const float c = wo.y * rsqrtf(nv.y + 1e-5f);
  wosv[(size_t)b * 32768 + f * 128 + e2] = packbf(a, c);
}

// ---------------- Kernel 4: vproj = vraw @ wosv[b]^T  (bf16 out, no bias) -------------------
__global__ __launch_bounds__(256, 2) void gemm_vproj(
    const __hip_bfloat16* __restrict__ A, const __hip_bfloat16* __restrict__ Wsv,
    __hip_bfloat16* __restrict__ Og) {
  __shared__ __align__(16) char As[8192];
  __shared__ __align__(16) char Bs[8192];
  const int t = threadIdx.x, lane = t & 63, wid = t >> 6;
  const int wm = (wid & 1) * 64, wn = (wid >> 1) * 64;
  const int l16 = lane & 15, q4 = lane >> 4;
  const int m0 = blockIdx.x * 128, n0 = blockIdx.y * 128;
  const int b = m0 >> 13;
  const __hip_bfloat16* W = Wsv + ((size_t)b << 16);
  floatx4 acc[4][4] = {};
  const int srow = wid * 16 + (lane >> 2);
  const int skoff = (lane & 3) * 8;
  const __hip_bfloat16* gA = A + (size_t)(m0 + srow) * D + skoff;
  const __hip_bfloat16* gB = W + (size_t)(n0 + srow) * D + skoff;
  char* lA = As + srow * 64 + skoff * 2;
  char* lB = Bs + srow * 64 + skoff * 2;
  for (int kt = 0; kt < 256; kt += 32) {
    gl_lds16(gA + kt, lA);
    gl_lds16(gA + kt + 64 * D, lA + 4096);
    gl_lds16(gB + kt, lB);
    gl_lds16(gB + kt + 64 * D, lB + 4096);
    __syncthreads();
    short8 af[4], bf8[4];
#pragma unroll
    for (int i = 0; i < 4; i++) {
      af[i]  = *(const short8*)(As + (wm + i * 16 + l16) * 64 + q4 * 16);
      bf8[i] = *(const short8*)(Bs + (wn + i * 16 + l16) * 64 + q4 * 16);
    }
#pragma unroll
    for (int i = 0; i < 4; i++)
#pragma unroll
      for (int j = 0; j < 4; j++)
        acc[i][j] = __builtin_amdgcn_mfma_f32_16x16x32_bf16(af[i], bf8[j], acc[i][j], 0, 0, 0);
    __syncthreads();
  }
#pragma unroll
  for (int j = 0; j < 4; j++) {
    const int colg = n0 + wn + j * 16 + l16;
#pragma unroll
    for (int i = 0; i < 4; i++) {
      const int rowg = m0 + wm + i * 16 + q4 * 4;
#pragma unroll
      for (int r = 0; r < 4; r++)
        Og[(size_t)(rowg + r) * D + colg] = __float2bfloat16(acc[i][j][r]);
    }
  }
}

// ---------------- Kernel 5: KVt[b][f][d] = sum_n vproj[n][f]*kw[n][d]  (TN, split-K) --------
__global__ __launch_bounds__(256, 2) void gemm_tn(
    const __hip_bfloat16* __restrict__ Vp, const __hip_bfloat16* __restrict__ Kwb,
    float* __restrict__ KVt) {
  __shared__ __align__(16) char sm[2 * 32 * 260];  // padded rows: 260B
  char* Asm = sm;
  char* Bsm = sm + 32 * 260;
  const int t = threadIdx.x, lane = t & 63, wid = t >> 6;
  const int wm = (wid & 1) * 64, wn = (wid >> 1) * 64;
  const int l16 = lane & 15, q4 = lane >> 4;
  const int chunk = blockIdx.x;            // 16 chunks of 512 tokens
  const int ed = blockIdx.y, b = blockIdx.z;
  const int e0 = (ed & 1) * 128, d0 = (ed >> 1) * 128;
  const uint32_t* V32 = (const uint32_t*)Vp;
  const uint32_t* K32 = (const uint32_t*)Kwb;
  floatx4 acc[4][4] = {};
  for (int nt = 0; nt < 512; nt += 32) {
    const int nbase = chunk * 512 + nt;
#pragma unroll
    for (int rep = 0; rep < 8; rep++) {
      const int flat = rep * 256 + t;
      const int nn = flat >> 6;
      const int e2 = flat & 63;
      const size_t src = ((size_t)b * NTOK + nbase + nn) * 128;
      *(uint32_t*)(Asm + nn * 260 + e2 * 4) = V32[src + (e0 >> 1) + e2];
      *(uint32_t*)(Bsm + nn * 260 + e2 * 4) = K32[src + (d0 >> 1) + e2];
    }
    __syncthreads();
    short8 af[4], bf8[4];
#pragma unroll
    for (int i = 0; i < 4; i++) {
#pragma unroll
      for (int jj = 0; jj < 8; jj++) {
        af[i][jj]  = *(const short*)(Asm + (q4 * 8 + jj) * 260 + (wm + i * 16 + l16) * 2);
        bf8[i][jj] = *(const short*)(Bsm + (q4 * 8 + jj) * 260 + (wn + i * 16 + l16) * 2);
      }
    }
#pragma unroll
    for (int i = 0; i < 4; i++)
#pragma unroll
      for (int j = 0; j < 4; j++)
        acc[i][j] = __builtin_amdgcn_mfma_f32_16x16x32_bf16(af[i], bf8[j], acc[i][j], 0, 0, 0);
    __syncthreads();
  }
#pragma unroll
  for (int i = 0; i < 4; i++) {
#pragma unroll
    for (int r = 0; r < 4; r++) {
      const int eg = e0 + wm + i * 16 + q4 * 4 + r;
#pragma unroll
      for (int j = 0; j < 4; j++) {
        const int dg = d0 + wn + j * 16 + l16;
        atomicAdd(&KVt[((size_t)b * D + eg) * D + dg], acc[i][j][r]);
      }
    }
  }
}

// ---------------- Kernel 6: P = bf16(KVt)  (1 MB fp32 -> 512 KB bf16) -----------------------
__global__ __launch_bounds__(256) void kvt2bf(const float* __restrict__ KVt,
                                              uint32_t* __restrict__ P) {
  const int idx = blockIdx.x * 256 + threadIdx.x;  // pair index, 131072 total
  const float2 v = ((const float2*)KVt)[idx];
  P[idx] = packbf(v.x, v.y);
}

// ---------------- Kernel 7: out = q_rot @ P^T + bo  (fp32 out to d_out) ---------------------
__global__ __launch_bounds__(256, 2) void gemm_out(
    const __hip_bfloat16* __restrict__ A, const __hip_bfloat16* __restrict__ Pm,
    const float* __restrict__ bo, float* __restrict__ Og) {
  __shared__ __align__(16) char As[8192];
  __shared__ __align__(16) char Bs[8192];
  const int t = threadIdx.x, lane = t & 63, wid = t >> 6;
  const int wm = (wid & 1) * 64, wn = (wid >> 1) * 64;
  const int l16 = lane & 15, q4 = lane >> 4;
  const int m0 = blockIdx.x * 128, n0 = blockIdx.y * 128;
  const int b = m0 >> 13;
  const __hip_bfloat16* W = Pm + ((size_t)b << 16);
  floatx4 acc[4][4] = {};
  const int srow = wid * 16 + (lane >> 2);
  const int skoff = (lane & 3) * 8;
  const __hip_bfloat16* gA = A + (size_t)(m0 + srow) * D + skoff;
  const __hip_bfloat16* gB = W + (size_t)(n0 + srow) * D + skoff;
  char* lA = As + srow * 64 + skoff * 2;
  char* lB = Bs + srow * 64 + skoff * 2;
  for (int kt = 0; kt < 256; kt += 32) {
    gl_lds16(gA + kt, lA);
    gl_lds16(gA + kt + 64 * D, lA + 4096);
    gl_lds16(gB + kt, lB);
    gl_lds16(gB + kt + 64 * D, lB + 4096);
    __syncthreads();
    short8 af[4], bf8[4];
#pragma unroll
    for (int i = 0; i < 4; i++) {
      af[i]  = *(const short8*)(As + (wm + i * 16 + l16) * 64 + q4 * 16);
      bf8[i] = *(const short8*)(Bs + (wn + i * 16 + l16) * 64 + q4 * 16);
    }
#pragma unroll
    for (int i = 0; i < 4; i++)
#pragma unroll
      for (int j = 0; j < 4; j++)
        acc[i][j] = __builtin_amdgcn_mfma_f32_16x16x32_bf16(af[i], bf8[j], acc[i][j], 0, 0, 0);
    __syncthreads();
  }
#pragma unroll
  for (int j = 0; j < 4; j++) {
    const int colg = n0 + wn + j * 16 + l16;
    const float bb = bo[colg];
#pragma unroll
    for (int i = 0; i < 4; i++) {
      const int rowg = m0 + wm + i * 16 + q4 * 4;
#pragma unroll
      for (int r = 0; r < 4; r++)
        Og[(size_t)(rowg + r) * D + colg] = acc[i][j][r] + bb;
    }
  }
}

extern "C" void kernel_launch(void* const* d_in, const int* in_sizes, int n_in,
                              void* d_out, int out_size, void* d_ws, size_t ws_size,
                              hipStream_t stream) {
  const float* phi    = (const float*)d_in[0];
  const float* coords = (const float*)d_in[1];
  const float* wts    = (const float*)d_in[2];
  const float* bq     = (const float*)d_in[4];
  const float* bk     = (const float*)d_in[6];
  const float* bv     = (const float*)d_in[8];
  const float* Wo     = (const float*)d_in[9];
  const float* bo     = (const float*)d_in[10];
  const float* lift   = (const float*)d_in[11];

  char* ws = (char*)d_ws;
  __hip_bfloat16* phi16 = (__hip_bfloat16*)ws;            // 16 MiB
  __hip_bfloat16* W16   = (__hip_bfloat16*)(ws + 16777216);
  const size_t QOFF = 17170432;
  const size_t SZ = (size_t)MTOT * D * 2;  // 16 MiB per bf16 buffer
  __hip_bfloat16* Qb = (__hip_bfloat16*)(ws + QOFF);
  __hip_bfloat16* Kb = (__hip_bfloat16*)(ws + QOFF + SZ);
  __hip_bfloat16* Vb = (__hip_bfloat16*)(ws + QOFF + 2 * SZ);
  const size_t NOFF = QOFF + 3 * SZ;       // 67502080
  float* nsk = (float*)(ws + NOFF);
  float* nsv = (float*)(ws + NOFF + 4096);
  float* KVt = (float*)(ws + NOFF + 8192);                     // 1 MiB fp32
  __hip_bfloat16* P    = (__hip_bfloat16*)(ws + NOFF + 8192 + 1048576);      // 512 KiB
  __hip_bfloat16* wosv = (__hip_bfloat16*)(ws + NOFF + 8192 + 1048576 + 524288);
  __hip_bfloat16* vproj = (__hip_bfloat16*)(ws + NOFF + 8192 + 1048576 + 2 * 524288);  // 16 MiB

  // zero norm accumulators + KVt (atomicAdd targets)
  hipMemsetAsync(ws + NOFF, 0, 8192 + 1048576, stream);

  convert<<<16768, 256, 0, stream>>>(phi, (const float*)d_in[3], (const float*)d_in[5],
                                     (const float*)d_in[7], (uint32_t*)ws);
  gemm_qkv<<<dim3(256, 3), 256, 0, stream>>>(phi16, W16, bq, bk, bv, coords, wts, lift,
                                             Qb, Kb, Vb, nsk, nsv);
  pointwise_k<<<8192, 256, 0, stream>>>(Kb, coords, wts, lift, nsk);
  make_wosv<<<512, 256, 0, stream>>>(Wo, nsv, (uint32_t*)wosv);
  gemm_vproj<<<dim3(256, 2), 256, 0, stream>>>(Vb, wosv, vproj);
  gemm_tn<<<dim3(16, 4, 4), 256, 0, stream>>>(vproj, Kb, KVt);
  kvt2bf<<<512, 256, 0, stream>>>(KVt, (uint32_t*)P);
  gemm_out<<<dim3(256, 2), 256, 0, stream>>>(Qb, P, bo, (float*)d_out);
}

// Round 5
// 196.062 us; speedup vs baseline: 1.2033x; 1.0462x over previous
//
#include <hip/hip_runtime.h>
#include <hip/hip_bf16.h>
#include <stdint.h>

#define DEV __device__ __forceinline__

typedef short short8 __attribute__((ext_vector_type(8)));
typedef float floatx4 __attribute__((ext_vector_type(4)));
typedef uint32_t uint32x4 __attribute__((ext_vector_type(4)));

constexpr int D = 256;
constexpr int NTOK = 8192;
constexpr int MTOT = 4 * NTOK;  // 32768 rows total

DEV void gl_lds16(const void* g, void* l) {
  __builtin_amdgcn_global_load_lds(
      (const __attribute__((address_space(1))) void*)g,
      (__attribute__((address_space(3))) void*)l, 16, 0, 0);
}

DEV float bflo(uint32_t u) { return __uint_as_float(u << 16); }
DEV float bfhi(uint32_t u) { return __uint_as_float(u & 0xffff0000u); }
DEV uint32_t packbf(float a, float b) {
  uint16_t xa = __builtin_bit_cast(uint16_t, __float2bfloat16(a));
  uint16_t xb = __builtin_bit_cast(uint16_t, __float2bfloat16(b));
  return (uint32_t)xa | ((uint32_t)xb << 16);
}

// ---------------- Kernel 0: fp32 -> bf16 conversion of phi, Wq, Wk, Wv ----------------
constexpr int PHI_E = MTOT * D;          // 8388608
constexpr int W_E = D * D;               // 65536
__global__ __launch_bounds__(256) void convert(
    const float* __restrict__ phi, const float* __restrict__ Wq,
    const float* __restrict__ Wk, const float* __restrict__ Wv,
    uint32_t* __restrict__ dst) {
  const int idx2 = blockIdx.x * 256 + threadIdx.x;  // pair index
  const int e0 = idx2 * 2;
  float2 v;
  if (e0 < PHI_E) {
    v = ((const float2*)phi)[idx2];
  } else {
    int r = e0 - PHI_E;
    if (r < W_E) v = ((const float2*)Wq)[r >> 1];
    else if (r < 2 * W_E) v = ((const float2*)Wk)[(r - W_E) >> 1];
    else v = ((const float2*)Wv)[(r - 2 * W_E) >> 1];
  }
  dst[idx2] = packbf(v.x, v.y);
}

// ---------------- Kernel 1: fused QKV GEMM, 128x256 tile per block --------------------------
// blockIdx.y = mat (0=Q,1=K,2=V). Fuses: bias add; Q-rotary (fp32); w-weighted column norm
// partials for K/V (atomicAdd into nsk/nsv). K/V stored RAW psi.
__global__ __launch_bounds__(256, 2) void gemm_qkv(
    const __hip_bfloat16* __restrict__ phi,
    const __hip_bfloat16* __restrict__ W16,   // [Wq|Wk|Wv] bf16, row-major D x D each
    const float* __restrict__ bq, const float* __restrict__ bk, const float* __restrict__ bv,
    const float* __restrict__ coords, const float* __restrict__ wts,
    const float* __restrict__ lift,
    __hip_bfloat16* __restrict__ Qb, __hip_bfloat16* __restrict__ Kb,
    __hip_bfloat16* __restrict__ Vb, float* __restrict__ nsk, float* __restrict__ nsv) {
  __shared__ __align__(16) char As[8192];    // 128 rows x 64B (32 bf16 k-slice)
  __shared__ __align__(16) char Bs[16384];   // 256 rows x 64B
  const int t = threadIdx.x, lane = t & 63, wid = t >> 6;
  const int wm = (wid & 1) * 64, wn = (wid >> 1) * 64;
  const int l16 = lane & 15, q4 = lane >> 4;
  const int m0 = blockIdx.x * 128;
  const int mat = blockIdx.y;
  const __hip_bfloat16* W = W16 + (size_t)mat * W_E;
  const float* bias = (mat == 0) ? bq : (mat == 1) ? bk : bv;
  __hip_bfloat16* Out = (mat == 0) ? Qb : (mat == 1) ? Kb : Vb;

  floatx4 acc[4][8] = {};

  const int srow = wid * 16 + (lane >> 2);   // 0..63
  const int skoff = (lane & 3) * 8;
  const __hip_bfloat16* gA = phi + (size_t)(m0 + srow) * D + skoff;
  const __hip_bfloat16* gB = W + (size_t)srow * D + skoff;
  char* lA = As + srow * 64 + skoff * 2;
  char* lB = Bs + srow * 64 + skoff * 2;

  for (int kt = 0; kt < 256; kt += 32) {
    gl_lds16(gA + kt, lA);
    gl_lds16(gA + kt + 64 * D, lA + 4096);
    gl_lds16(gB + kt, lB);
    gl_lds16(gB + kt + 64 * D, lB + 4096);
    gl_lds16(gB + kt + 128 * D, lB + 8192);
    gl_lds16(gB + kt + 192 * D, lB + 12288);
    __syncthreads();
    short8 af[4], bf8[8];
#pragma unroll
    for (int i = 0; i < 4; i++)
      af[i] = *(const short8*)(As + (wm + i * 16 + l16) * 64 + q4 * 16);
#pragma unroll
    for (int j = 0; j < 8; j++) {
      const int col = wn + (j & 3) * 16 + (j >> 2) * 128 + l16;
      bf8[j] = *(const short8*)(Bs + col * 64 + q4 * 16);
    }
#pragma unroll
    for (int i = 0; i < 4; i++)
#pragma unroll
      for (int j = 0; j < 8; j++)
        acc[i][j] = __builtin_amdgcn_mfma_f32_16x16x32_bf16(af[i], bf8[j], acc[i][j], 0, 0, 0);
    __syncthreads();
  }

  float bcol[8];
#pragma unroll
  for (int j = 0; j < 8; j++)
    bcol[j] = bias[wn + (j & 3) * 16 + (j >> 2) * 128 + l16];

  if (mat == 0) {
    // Q: add bias, apply rotary in fp32, store bf16
    float lx[4], ly[4], lz[4];
#pragma unroll
    for (int jj = 0; jj < 4; jj++) {
      const int c = wn + jj * 16 + l16;  // pair index 0..127
      lx[jj] = lift[c * 3 + 0]; ly[jj] = lift[c * 3 + 1]; lz[jj] = lift[c * 3 + 2];
    }
#pragma unroll
    for (int i = 0; i < 4; i++) {
#pragma unroll
      for (int r = 0; r < 4; r++) {
        const int row = m0 + wm + i * 16 + q4 * 4 + r;
        const float cx = coords[row * 3 + 0];
        const float cy = coords[row * 3 + 1];
        const float cz = coords[row * 3 + 2];
#pragma unroll
        for (int jj = 0; jj < 4; jj++) {
          const int c = wn + jj * 16 + l16;
          const float p = cx * lx[jj] + cy * ly[jj] + cz * lz[jj];
          float s, cs;
          __sincosf(p, &s, &cs);
          const float f1 = acc[i][jj][r] + bcol[jj];
          const float f2 = acc[i][jj + 4][r] + bcol[jj + 4];
          Out[(size_t)row * D + c]       = __float2bfloat16(f1 * cs - f2 * s);
          Out[(size_t)row * D + c + 128] = __float2bfloat16(f1 * s + f2 * cs);
        }
      }
    }
  } else {
    // K/V: add bias, store raw psi bf16, accumulate w-weighted column norms
    const int b = m0 >> 13;
    float* ns = (mat == 1) ? nsk : nsv;
    float colsum[8] = {};
#pragma unroll
    for (int i = 0; i < 4; i++) {
#pragma unroll
      for (int r = 0; r < 4; r++) {
        const int row = m0 + wm + i * 16 + q4 * 4 + r;
        const float w = wts[row];
#pragma unroll
        for (int j = 0; j < 8; j++) {
          const int col = wn + (j & 3) * 16 + (j >> 2) * 128 + l16;
          const float psi = acc[i][j][r] + bcol[j];
          Out[(size_t)row * D + col] = __float2bfloat16(psi);
          colsum[j] += w * psi * psi;
        }
      }
    }
#pragma unroll
    for (int j = 0; j < 8; j++) {
      float s = colsum[j];
      s += __shfl_xor(s, 16);
      s += __shfl_xor(s, 32);
      if (q4 == 0) {
        const int col = wn + (j & 3) * 16 + (j >> 2) * 128 + l16;
        atomicAdd(&ns[b * D + col], s);
      }
    }
  }
}

// ---------------- Kernel 2: fused vproj-GEMM + K-pointwise (grid fusion) --------------------
// blocks [0,512): vproj = Vraw @ (Wo*rsqrt(nsv))^T, wosv computed inline during B-staging.
// blocks [512,640): K pointwise basis_norm -> rotary -> *w, 256 rows per block.
__global__ __launch_bounds__(256, 2) void vproj_pk(
    const __hip_bfloat16* __restrict__ Vb, const float* __restrict__ Wo,
    const float* __restrict__ nsv, __hip_bfloat16* __restrict__ vproj,
    __hip_bfloat16* __restrict__ Kb, const float* __restrict__ coords,
    const float* __restrict__ wts, const float* __restrict__ lift,
    const float* __restrict__ nsk) {
  __shared__ __align__(16) char As[8192];
  __shared__ __align__(16) char Bs[8192];
  __shared__ __align__(16) float isv[256];
  const int bx = blockIdx.x;
  const int t = threadIdx.x;

  if (bx < 512) {
    const int lane = t & 63, wid = t >> 6;
    const int wm = (wid & 1) * 64, wn = (wid >> 1) * 64;
    const int l16 = lane & 15, q4 = lane >> 4;
    const int m0 = (bx >> 1) * 128, n0 = (bx & 1) * 128;
    const int b = m0 >> 13;
    isv[t] = rsqrtf(nsv[b * D + t] + 1e-5f);
    __syncthreads();
    floatx4 acc[4][4] = {};
    const int srow = wid * 16 + (lane >> 2);
    const int skoff = (lane & 3) * 8;
    const __hip_bfloat16* gA = Vb + (size_t)(m0 + srow) * D + skoff;
    const float* gB0 = Wo + (size_t)(n0 + srow) * D + skoff;
    const float* gB1 = Wo + (size_t)(n0 + srow + 64) * D + skoff;
    char* lA = As + srow * 64 + skoff * 2;
    char* lB = Bs + srow * 64 + skoff * 2;
    for (int kt = 0; kt < 256; kt += 32) {
      gl_lds16(gA + kt, lA);
      gl_lds16(gA + kt + 64 * D, lA + 4096);
      // B staging: wosv = Wo * isv (bf16)
      const float4 w0 = *(const float4*)(gB0 + kt);
      const float4 w1 = *(const float4*)(gB0 + kt + 4);
      const float4 w2 = *(const float4*)(gB1 + kt);
      const float4 w3 = *(const float4*)(gB1 + kt + 4);
      const float4 i0 = *(const float4*)(&isv[kt + skoff]);
      const float4 i1 = *(const float4*)(&isv[kt + skoff + 4]);
      uint32x4 p0, p1;
      p0[0] = packbf(w0.x * i0.x, w0.y * i0.y);
      p0[1] = packbf(w0.z * i0.z, w0.w * i0.w);
      p0[2] = packbf(w1.x * i1.x, w1.y * i1.y);
      p0[3] = packbf(w1.z * i1.z, w1.w * i1.w);
      p1[0] = packbf(w2.x * i0.x, w2.y * i0.y);
      p1[1] = packbf(w2.z * i0.z, w2.w * i0.w);
      p1[2] = packbf(w3.x * i1.x, w3.y * i1.y);
      p1[3] = packbf(w3.z * i1.z, w3.w * i1.w);
      *(uint32x4*)lB = p0;
      *(uint32x4*)(lB + 4096) = p1;
      __syncthreads();
      short8 af[4], bf8[4];
#pragma unroll
      for (int i = 0; i < 4; i++) {
        af[i]  = *(const short8*)(As + (wm + i * 16 + l16) * 64 + q4 * 16);
        bf8[i] = *(const short8*)(Bs + (wn + i * 16 + l16) * 64 + q4 * 16);
      }
#pragma unroll
      for (int i = 0; i < 4; i++)
#pragma unroll
        for (int j = 0; j < 4; j++)
          acc[i][j] = __builtin_amdgcn_mfma_f32_16x16x32_bf16(af[i], bf8[j], acc[i][j], 0, 0, 0);
      __syncthreads();
    }
#pragma unroll
    for (int j = 0; j < 4; j++) {
      const int colg = n0 + wn + j * 16 + l16;
#pragma unroll
      for (int i = 0; i < 4; i++) {
        const int rowg = m0 + wm + i * 16 + q4 * 4;
#pragma unroll
        for (int r = 0; r < 4; r++)
          vproj[(size_t)(rowg + r) * D + colg] = __float2bfloat16(acc[i][j][r]);
      }
    }
  } else {
    // ---- K pointwise: 256 rows per block ----
    const int j = t & 63, rloc = t >> 6;
    const int pb = bx - 512;
    const int r0 = pb * 256;
    const int b = r0 >> 13;                 // constant within block (256 | 8192)
    const int j0 = 2 * j, j1 = 2 * j + 1;
    const float lx0 = lift[j0 * 3 + 0], ly0 = lift[j0 * 3 + 1], lz0 = lift[j0 * 3 + 2];
    const float lx1 = lift[j1 * 3 + 0], ly1 = lift[j1 * 3 + 1], lz1 = lift[j1 * 3 + 2];
    const int nb = b * D;
    const float ik0 = rsqrtf(nsk[nb + j0] + 1e-5f);
    const float ik1 = rsqrtf(nsk[nb + j1] + 1e-5f);
    const float ik2 = rsqrtf(nsk[nb + 128 + j0] + 1e-5f);
    const float ik3 = rsqrtf(nsk[nb + 128 + j1] + 1e-5f);
    uint32_t* K32 = (uint32_t*)Kb;
    for (int it = 0; it < 64; it++) {
      const size_t row = (size_t)r0 + it * 4 + rloc;
      const float cx = coords[row * 3 + 0];
      const float cy = coords[row * 3 + 1];
      const float cz = coords[row * 3 + 2];
      const float p0 = cx * lx0 + cy * ly0 + cz * lz0;
      const float p1 = cx * lx1 + cy * ly1 + cz * lz1;
      float s0, c0, s1, c1;
      __sincosf(p0, &s0, &c0);
      __sincosf(p1, &s1, &c1);
      const float w = wts[row];
      const size_t base = row * 128;
      const uint32_t klo = K32[base + j], khi = K32[base + 64 + j];
      const float k1a = bflo(klo) * ik0, k1b = bfhi(klo) * ik1;
      const float k2a = bflo(khi) * ik2, k2b = bfhi(khi) * ik3;
      K32[base + j]      = packbf((k1a * c0 - k2a * s0) * w, (k1b * c1 - k2b * s1) * w);
      K32[base + 64 + j] = packbf((k1a * s0 + k2a * c0) * w, (k1b * s1 + k2b * c1) * w);
    }
  }
}

// ---------------- Kernel 3: part[chunk][b][e][d] = sum_{n in chunk} vproj[n][e]*kw[n][d] ----
// 32 chunks of 256 tokens; plain stores (no atomics).
__global__ __launch_bounds__(256, 2) void gemm_tn(
    const __hip_bfloat16* __restrict__ Vp, const __hip_bfloat16* __restrict__ Kwb,
    float* __restrict__ part) {
  __shared__ __align__(16) char sm[2 * 32 * 260];  // padded rows: 260B
  char* Asm = sm;
  char* Bsm = sm + 32 * 260;
  const int t = threadIdx.x, lane = t & 63, wid = t >> 6;
  const int wm = (wid & 1) * 64, wn = (wid >> 1) * 64;
  const int l16 = lane & 15, q4 = lane >> 4;
  const int chunk = blockIdx.x;            // 0..31
  const int ed = blockIdx.y, b = blockIdx.z;
  const int e0 = (ed & 1) * 128, d0 = (ed >> 1) * 128;
  const uint32_t* V32 = (const uint32_t*)Vp;
  const uint32_t* K32 = (const uint32_t*)Kwb;
  floatx4 acc[4][4] = {};
  for (int nt = 0; nt < 256; nt += 32) {
    const int nbase = chunk * 256 + nt;
#pragma unroll
    for (int rep = 0; rep < 8; rep++) {
      const int flat = rep * 256 + t;
      const int nn = flat >> 6;
      const int e2 = flat & 63;
      const size_t src = ((size_t)b * NTOK + nbase + nn) * 128;
      *(uint32_t*)(Asm + nn * 260 + e2 * 4) = V32[src + (e0 >> 1) + e2];
      *(uint32_t*)(Bsm + nn * 260 + e2 * 4) = K32[src + (d0 >> 1) + e2];
    }
    __syncthreads();
    short8 af[4], bf8[4];
#pragma unroll
    for (int i = 0; i < 4; i++) {
#pragma unroll
      for (int jj = 0; jj < 8; jj++) {
        af[i][jj]  = *(const short*)(Asm + (q4 * 8 + jj) * 260 + (wm + i * 16 + l16) * 2);
        bf8[i][jj] = *(const short*)(Bsm + (q4 * 8 + jj) * 260 + (wn + i * 16 + l16) * 2);
      }
    }
#pragma unroll
    for (int i = 0; i < 4; i++)
#pragma unroll
      for (int j = 0; j < 4; j++)
        acc[i][j] = __builtin_amdgcn_mfma_f32_16x16x32_bf16(af[i], bf8[j], acc[i][j], 0, 0, 0);
    __syncthreads();
  }
  float* pt = part + (((size_t)(chunk * 4 + b)) << 16);
#pragma unroll
  for (int i = 0; i < 4; i++) {
#pragma unroll
    for (int r = 0; r < 4; r++) {
      const int eg = e0 + wm + i * 16 + q4 * 4 + r;
#pragma unroll
      for (int j = 0; j < 4; j++) {
        const int dg = d0 + wn + j * 16 + l16;
        pt[eg * 256 + dg] = acc[i][j][r];
      }
    }
  }
}

// ---------------- Kernel 4: P[b] = bf16( sum_chunks part[chunk][b] ) ------------------------
__global__ __launch_bounds__(256) void reduce_kvt(const float* __restrict__ part,
                                                  uint32_t* __restrict__ P) {
  const int flat2 = blockIdx.x * 256 + threadIdx.x;  // float2 index over [4][32768]
  const int b = flat2 >> 15;
  const int off2 = flat2 & 32767;
  const float2* p2 = (const float2*)part;
  float sx = 0, sy = 0;
#pragma unroll
  for (int c = 0; c < 32; c++) {
    const float2 v = p2[(((size_t)(c * 4 + b)) << 15) + off2];
    sx += v.x; sy += v.y;
  }
  P[flat2] = packbf(sx, sy);
}

// ---------------- Kernel 5: out = q_rot @ P^T + bo  (fp32 out to d_out) ---------------------
__global__ __launch_bounds__(256, 2) void gemm_out(
    const __hip_bfloat16* __restrict__ A, const __hip_bfloat16* __restrict__ Pm,
    const float* __restrict__ bo, float* __restrict__ Og) {
  __shared__ __align__(16) char As[8192];
  __shared__ __align__(16) char Bs[8192];
  const int t = threadIdx.x, lane = t & 63, wid = t >> 6;
  const int wm = (wid & 1) * 64, wn = (wid >> 1) * 64;
  const int l16 = lane & 15, q4 = lane >> 4;
  const int m0 = blockIdx.x * 128, n0 = blockIdx.y * 128;
  const int b = m0 >> 13;
  const __hip_bfloat16* W = Pm + ((size_t)b << 16);
  floatx4 acc[4][4] = {};
  const int srow = wid * 16 + (lane >> 2);
  const int skoff = (lane & 3) * 8;
  const __hip_bfloat16* gA = A + (size_t)(m0 + srow) * D + skoff;
  const __hip_bfloat16* gB = W + (size_t)(n0 + srow) * D + skoff;
  char* lA = As + srow * 64 + skoff * 2;
  char* lB = Bs + srow * 64 + skoff * 2;
  for (int kt = 0; kt < 256; kt += 32) {
    gl_lds16(gA + kt, lA);
    gl_lds16(gA + kt + 64 * D, lA + 4096);
    gl_lds16(gB + kt, lB);
    gl_lds16(gB + kt + 64 * D, lB + 4096);
    __syncthreads();
    short8 af[4], bf8[4];
#pragma unroll
    for (int i = 0; i < 4; i++) {
      af[i]  = *(const short8*)(As + (wm + i * 16 + l16) * 64 + q4 * 16);
      bf8[i] = *(const short8*)(Bs + (wn + i * 16 + l16) * 64 + q4 * 16);
    }
#pragma unroll
    for (int i = 0; i < 4; i++)
#pragma unroll
      for (int j = 0; j < 4; j++)
        acc[i][j] = __builtin_amdgcn_mfma_f32_16x16x32_bf16(af[i], bf8[j], acc[i][j], 0, 0, 0);
    __syncthreads();
  }
#pragma unroll
  for (int j = 0; j < 4; j++) {
    const int colg = n0 + wn + j * 16 + l16;
    const float bb = bo[colg];
#pragma unroll
    for (int i = 0; i < 4; i++) {
      const int rowg = m0 + wm + i * 16 + q4 * 4;
#pragma unroll
      for (int r = 0; r < 4; r++)
        Og[(size_t)(rowg + r) * D + colg] = acc[i][j][r] + bb;
    }
  }
}

extern "C" void kernel_launch(void* const* d_in, const int* in_sizes, int n_in,
                              void* d_out, int out_size, void* d_ws, size_t ws_size,
                              hipStream_t stream) {
  const float* phi    = (const float*)d_in[0];
  const float* coords = (const float*)d_in[1];
  const float* wts    = (const float*)d_in[2];
  const float* bq     = (const float*)d_in[4];
  const float* bk     = (const float*)d_in[6];
  const float* bv     = (const float*)d_in[8];
  const float* Wo     = (const float*)d_in[9];
  const float* bo     = (const float*)d_in[10];
  const float* lift   = (const float*)d_in[11];

  char* ws = (char*)d_ws;
  __hip_bfloat16* phi16 = (__hip_bfloat16*)ws;            // 16 MiB
  __hip_bfloat16* W16   = (__hip_bfloat16*)(ws + 16777216);
  const size_t QOFF = 17170432;
  const size_t SZ = (size_t)MTOT * D * 2;  // 16 MiB per bf16 buffer
  __hip_bfloat16* Qb = (__hip_bfloat16*)(ws + QOFF);
  __hip_bfloat16* Kb = (__hip_bfloat16*)(ws + QOFF + SZ);
  __hip_bfloat16* Vb = (__hip_bfloat16*)(ws + QOFF + 2 * SZ);
  const size_t NOFF = QOFF + 3 * SZ;       // 67502080
  float* nsk = (float*)(ws + NOFF);
  float* nsv = (float*)(ws + NOFF + 4096);
  float* part = (float*)(ws + NOFF + 8192);                          // 32 MiB partials
  __hip_bfloat16* P = (__hip_bfloat16*)(ws + NOFF + 8192 + 33554432);      // 512 KiB
  __hip_bfloat16* vproj = (__hip_bfloat16*)(ws + NOFF + 8192 + 33554432 + 524288);  // 16 MiB

  // zero norm accumulators only (the only atomicAdd targets)
  hipMemsetAsync(ws + NOFF, 0, 8192, stream);

  convert<<<16768, 256, 0, stream>>>(phi, (const float*)d_in[3], (const float*)d_in[5],
                                     (const float*)d_in[7], (uint32_t*)ws);
  gemm_qkv<<<dim3(256, 3), 256, 0, stream>>>(phi16, W16, bq, bk, bv, coords, wts, lift,
                                             Qb, Kb, Vb, nsk, nsv);
  vproj_pk<<<640, 256, 0, stream>>>(Vb, Wo, nsv, vproj, Kb, coords, wts, lift, nsk);
  gemm_tn<<<dim3(32, 4, 4), 256, 0, stream>>>(vproj, Kb, part);
  reduce_kvt<<<512, 256, 0, stream>>>(part, (uint32_t*)P);
  gemm_out<<<dim3(256, 2), 256, 0, stream>>>(Qb, P, bo, (float*)d_out);
}

// Round 6
// 191.042 us; speedup vs baseline: 1.2349x; 1.0263x over previous
//
#include <hip/hip_runtime.h>
#include <hip/hip_bf16.h>
#include <stdint.h>

#define DEV __device__ __forceinline__

typedef short short8 __attribute__((ext_vector_type(8)));
typedef float floatx4 __attribute__((ext_vector_type(4)));
typedef uint32_t uint32x4 __attribute__((ext_vector_type(4)));

constexpr int D = 256;
constexpr int NTOK = 8192;
constexpr int MTOT = 4 * NTOK;  // 32768 rows total

DEV void gl_lds16(const void* g, void* l) {
  __builtin_amdgcn_global_load_lds(
      (const __attribute__((address_space(1))) void*)g,
      (__attribute__((address_space(3))) void*)l, 16, 0, 0);
}

DEV float bflo(uint32_t u) { return __uint_as_float(u << 16); }
DEV float bfhi(uint32_t u) { return __uint_as_float(u & 0xffff0000u); }
DEV uint32_t packbf(float a, float b) {
  uint16_t xa = __builtin_bit_cast(uint16_t, __float2bfloat16(a));
  uint16_t xb = __builtin_bit_cast(uint16_t, __float2bfloat16(b));
  return (uint32_t)xa | ((uint32_t)xb << 16);
}

// ---------------- Kernel 0: fp32 -> bf16 conversion of phi, Wq, Wk, Wv + ns zeroing ---------
constexpr int PHI_E = MTOT * D;          // 8388608
constexpr int W_E = D * D;               // 65536
__global__ __launch_bounds__(256) void convert(
    const float* __restrict__ phi, const float* __restrict__ Wq,
    const float* __restrict__ Wk, const float* __restrict__ Wv,
    uint32_t* __restrict__ dst, float2* __restrict__ nszero) {
  if (blockIdx.x == 0) {
    // zero nsk/nsv accumulators (8 KB = 1024 float2)
    const float2 z = {0.f, 0.f};
#pragma unroll
    for (int k = 0; k < 4; k++) nszero[k * 256 + threadIdx.x] = z;
  }
  const int idx2 = blockIdx.x * 256 + threadIdx.x;  // pair index
  const int e0 = idx2 * 2;
  float2 v;
  if (e0 < PHI_E) {
    v = ((const float2*)phi)[idx2];
  } else {
    int r = e0 - PHI_E;
    if (r < W_E) v = ((const float2*)Wq)[r >> 1];
    else if (r < 2 * W_E) v = ((const float2*)Wk)[(r - W_E) >> 1];
    else v = ((const float2*)Wv)[(r - 2 * W_E) >> 1];
  }
  dst[idx2] = packbf(v.x, v.y);
}

// ---------------- Kernel 1: fused QKV GEMM, 128x256 tile per block --------------------------
__global__ __launch_bounds__(256, 2) void gemm_qkv(
    const __hip_bfloat16* __restrict__ phi,
    const __hip_bfloat16* __restrict__ W16,
    const float* __restrict__ bq, const float* __restrict__ bk, const float* __restrict__ bv,
    const float* __restrict__ coords, const float* __restrict__ wts,
    const float* __restrict__ lift,
    __hip_bfloat16* __restrict__ Qb, __hip_bfloat16* __restrict__ Kb,
    __hip_bfloat16* __restrict__ Vb, float* __restrict__ nsk, float* __restrict__ nsv) {
  __shared__ __align__(16) char As[8192];
  __shared__ __align__(16) char Bs[16384];
  const int t = threadIdx.x, lane = t & 63, wid = t >> 6;
  const int wm = (wid & 1) * 64, wn = (wid >> 1) * 64;
  const int l16 = lane & 15, q4 = lane >> 4;
  const int m0 = blockIdx.x * 128;
  const int mat = blockIdx.y;
  const __hip_bfloat16* W = W16 + (size_t)mat * W_E;
  const float* bias = (mat == 0) ? bq : (mat == 1) ? bk : bv;
  __hip_bfloat16* Out = (mat == 0) ? Qb : (mat == 1) ? Kb : Vb;

  floatx4 acc[4][8] = {};

  const int srow = wid * 16 + (lane >> 2);
  const int skoff = (lane & 3) * 8;
  const __hip_bfloat16* gA = phi + (size_t)(m0 + srow) * D + skoff;
  const __hip_bfloat16* gB = W + (size_t)srow * D + skoff;
  char* lA = As + srow * 64 + skoff * 2;
  char* lB = Bs + srow * 64 + skoff * 2;

  for (int kt = 0; kt < 256; kt += 32) {
    gl_lds16(gA + kt, lA);
    gl_lds16(gA + kt + 64 * D, lA + 4096);
    gl_lds16(gB + kt, lB);
    gl_lds16(gB + kt + 64 * D, lB + 4096);
    gl_lds16(gB + kt + 128 * D, lB + 8192);
    gl_lds16(gB + kt + 192 * D, lB + 12288);
    __syncthreads();
    short8 af[4], bf8[8];
#pragma unroll
    for (int i = 0; i < 4; i++)
      af[i] = *(const short8*)(As + (wm + i * 16 + l16) * 64 + q4 * 16);
#pragma unroll
    for (int j = 0; j < 8; j++) {
      const int col = wn + (j & 3) * 16 + (j >> 2) * 128 + l16;
      bf8[j] = *(const short8*)(Bs + col * 64 + q4 * 16);
    }
#pragma unroll
    for (int i = 0; i < 4; i++)
#pragma unroll
      for (int j = 0; j < 8; j++)
        acc[i][j] = __builtin_amdgcn_mfma_f32_16x16x32_bf16(af[i], bf8[j], acc[i][j], 0, 0, 0);
    __syncthreads();
  }

  float bcol[8];
#pragma unroll
  for (int j = 0; j < 8; j++)
    bcol[j] = bias[wn + (j & 3) * 16 + (j >> 2) * 128 + l16];

  if (mat == 0) {
    float lx[4], ly[4], lz[4];
#pragma unroll
    for (int jj = 0; jj < 4; jj++) {
      const int c = wn + jj * 16 + l16;
      lx[jj] = lift[c * 3 + 0]; ly[jj] = lift[c * 3 + 1]; lz[jj] = lift[c * 3 + 2];
    }
#pragma unroll
    for (int i = 0; i < 4; i++) {
#pragma unroll
      for (int r = 0; r < 4; r++) {
        const int row = m0 + wm + i * 16 + q4 * 4 + r;
        const float cx = coords[row * 3 + 0];
        const float cy = coords[row * 3 + 1];
        const float cz = coords[row * 3 + 2];
#pragma unroll
        for (int jj = 0; jj < 4; jj++) {
          const int c = wn + jj * 16 + l16;
          const float p = cx * lx[jj] + cy * ly[jj] + cz * lz[jj];
          float s, cs;
          __sincosf(p, &s, &cs);
          const float f1 = acc[i][jj][r] + bcol[jj];
          const float f2 = acc[i][jj + 4][r] + bcol[jj + 4];
          Out[(size_t)row * D + c]       = __float2bfloat16(f1 * cs - f2 * s);
          Out[(size_t)row * D + c + 128] = __float2bfloat16(f1 * s + f2 * cs);
        }
      }
    }
  } else {
    const int b = m0 >> 13;
    float* ns = (mat == 1) ? nsk : nsv;
    float colsum[8] = {};
#pragma unroll
    for (int i = 0; i < 4; i++) {
#pragma unroll
      for (int r = 0; r < 4; r++) {
        const int row = m0 + wm + i * 16 + q4 * 4 + r;
        const float w = wts[row];
#pragma unroll
        for (int j = 0; j < 8; j++) {
          const int col = wn + (j & 3) * 16 + (j >> 2) * 128 + l16;
          const float psi = acc[i][j][r] + bcol[j];
          Out[(size_t)row * D + col] = __float2bfloat16(psi);
          colsum[j] += w * psi * psi;
        }
      }
    }
#pragma unroll
    for (int j = 0; j < 8; j++) {
      float s = colsum[j];
      s += __shfl_xor(s, 16);
      s += __shfl_xor(s, 32);
      if (q4 == 0) {
        const int col = wn + (j & 3) * 16 + (j >> 2) * 128 + l16;
        atomicAdd(&ns[b * D + col], s);
      }
    }
  }
}

// ---------------- Kernel 2: fused vproj-GEMM + K-pointwise (grid fusion) --------------------
__global__ __launch_bounds__(256, 2) void vproj_pk(
    const __hip_bfloat16* __restrict__ Vb, const float* __restrict__ Wo,
    const float* __restrict__ nsv, __hip_bfloat16* __restrict__ vproj,
    __hip_bfloat16* __restrict__ Kb, const float* __restrict__ coords,
    const float* __restrict__ wts, const float* __restrict__ lift,
    const float* __restrict__ nsk) {
  __shared__ __align__(16) char As[8192];
  __shared__ __align__(16) char Bs[8192];
  __shared__ __align__(16) float isv[256];
  const int bx = blockIdx.x;
  const int t = threadIdx.x;

  if (bx < 512) {
    const int lane = t & 63, wid = t >> 6;
    const int wm = (wid & 1) * 64, wn = (wid >> 1) * 64;
    const int l16 = lane & 15, q4 = lane >> 4;
    const int m0 = (bx >> 1) * 128, n0 = (bx & 1) * 128;
    const int b = m0 >> 13;
    isv[t] = rsqrtf(nsv[b * D + t] + 1e-5f);
    __syncthreads();
    floatx4 acc[4][4] = {};
    const int srow = wid * 16 + (lane >> 2);
    const int skoff = (lane & 3) * 8;
    const __hip_bfloat16* gA = Vb + (size_t)(m0 + srow) * D + skoff;
    const float* gB0 = Wo + (size_t)(n0 + srow) * D + skoff;
    const float* gB1 = Wo + (size_t)(n0 + srow + 64) * D + skoff;
    char* lA = As + srow * 64 + skoff * 2;
    char* lB = Bs + srow * 64 + skoff * 2;
    for (int kt = 0; kt < 256; kt += 32) {
      gl_lds16(gA + kt, lA);
      gl_lds16(gA + kt + 64 * D, lA + 4096);
      const float4 w0 = *(const float4*)(gB0 + kt);
      const float4 w1 = *(const float4*)(gB0 + kt + 4);
      const float4 w2 = *(const float4*)(gB1 + kt);
      const float4 w3 = *(const float4*)(gB1 + kt + 4);
      const float4 i0 = *(const float4*)(&isv[kt + skoff]);
      const float4 i1 = *(const float4*)(&isv[kt + skoff + 4]);
      uint32x4 p0, p1;
      p0[0] = packbf(w0.x * i0.x, w0.y * i0.y);
      p0[1] = packbf(w0.z * i0.z, w0.w * i0.w);
      p0[2] = packbf(w1.x * i1.x, w1.y * i1.y);
      p0[3] = packbf(w1.z * i1.z, w1.w * i1.w);
      p1[0] = packbf(w2.x * i0.x, w2.y * i0.y);
      p1[1] = packbf(w2.z * i0.z, w2.w * i0.w);
      p1[2] = packbf(w3.x * i1.x, w3.y * i1.y);
      p1[3] = packbf(w3.z * i1.z, w3.w * i1.w);
      *(uint32x4*)lB = p0;
      *(uint32x4*)(lB + 4096) = p1;
      __syncthreads();
      short8 af[4], bf8[4];
#pragma unroll
      for (int i = 0; i < 4; i++) {
        af[i]  = *(const short8*)(As + (wm + i * 16 + l16) * 64 + q4 * 16);
        bf8[i] = *(const short8*)(Bs + (wn + i * 16 + l16) * 64 + q4 * 16);
      }
#pragma unroll
      for (int i = 0; i < 4; i++)
#pragma unroll
        for (int j = 0; j < 4; j++)
          acc[i][j] = __builtin_amdgcn_mfma_f32_16x16x32_bf16(af[i], bf8[j], acc[i][j], 0, 0, 0);
      __syncthreads();
    }
#pragma unroll
    for (int j = 0; j < 4; j++) {
      const int colg = n0 + wn + j * 16 + l16;
#pragma unroll
      for (int i = 0; i < 4; i++) {
        const int rowg = m0 + wm + i * 16 + q4 * 4;
#pragma unroll
        for (int r = 0; r < 4; r++)
          vproj[(size_t)(rowg + r) * D + colg] = __float2bfloat16(acc[i][j][r]);
      }
    }
  } else {
    const int j = t & 63, rloc = t >> 6;
    const int pb = bx - 512;
    const int r0 = pb * 256;
    const int b = r0 >> 13;
    const int j0 = 2 * j, j1 = 2 * j + 1;
    const float lx0 = lift[j0 * 3 + 0], ly0 = lift[j0 * 3 + 1], lz0 = lift[j0 * 3 + 2];
    const float lx1 = lift[j1 * 3 + 0], ly1 = lift[j1 * 3 + 1], lz1 = lift[j1 * 3 + 2];
    const int nb = b * D;
    const float ik0 = rsqrtf(nsk[nb + j0] + 1e-5f);
    const float ik1 = rsqrtf(nsk[nb + j1] + 1e-5f);
    const float ik2 = rsqrtf(nsk[nb + 128 + j0] + 1e-5f);
    const float ik3 = rsqrtf(nsk[nb + 128 + j1] + 1e-5f);
    uint32_t* K32 = (uint32_t*)Kb;
    for (int it = 0; it < 64; it++) {
      const size_t row = (size_t)r0 + it * 4 + rloc;
      const float cx = coords[row * 3 + 0];
      const float cy = coords[row * 3 + 1];
      const float cz = coords[row * 3 + 2];
      const float p0 = cx * lx0 + cy * ly0 + cz * lz0;
      const float p1 = cx * lx1 + cy * ly1 + cz * lz1;
      float s0, c0, s1, c1;
      __sincosf(p0, &s0, &c0);
      __sincosf(p1, &s1, &c1);
      const float w = wts[row];
      const size_t base = row * 128;
      const uint32_t klo = K32[base + j], khi = K32[base + 64 + j];
      const float k1a = bflo(klo) * ik0, k1b = bfhi(klo) * ik1;
      const float k2a = bflo(khi) * ik2, k2b = bfhi(khi) * ik3;
      K32[base + j]      = packbf((k1a * c0 - k2a * s0) * w, (k1b * c1 - k2b * s1) * w);
      K32[base + 64 + j] = packbf((k1a * s0 + k2a * c0) * w, (k1b * s1 + k2b * c1) * w);
    }
  }
}

// ---------------- Kernel 3: part[chunk][b] partial KVt, transposed-LDS MFMA, bf16 out -------
// LDS layout: [e][token] rows padded to 80B -> fragment loads are ds_read_b128.
__global__ __launch_bounds__(256, 2) void gemm_tn(
    const __hip_bfloat16* __restrict__ Vp, const __hip_bfloat16* __restrict__ Kwb,
    __hip_bfloat16* __restrict__ part) {
  __shared__ __align__(16) char Asm[128 * 80];
  __shared__ __align__(16) char Bsm[128 * 80];
  const int t = threadIdx.x, lane = t & 63, wid = t >> 6;
  const int wm = (wid & 1) * 64, wn = (wid >> 1) * 64;
  const int l16 = lane & 15, q4 = lane >> 4;
  const int chunk = blockIdx.x, ed = blockIdx.y, b = blockIdx.z;
  const int e0 = (ed & 1) * 128, d0 = (ed >> 1) * 128;
  const uint32_t* V32 = (const uint32_t*)Vp;
  const uint32_t* K32 = (const uint32_t*)Kwb;
  // staging assignment: token-pair np (xor-permuted for conflict-free LDS writes), col e2
  const int s_np = (((t & 3) | ((t >> 6) << 2)) ^ ((t >> 4) & 3));  // 0..15
  const int s_e2lo = (t >> 2) & 15;                                  // + 16*r -> 0..63
  floatx4 acc[4][4] = {};
  for (int nt = 0; nt < 256; nt += 32) {
    const int nbase = chunk * 256 + nt;
    const size_t tokbase = ((size_t)b * NTOK + nbase + 2 * s_np) * 128;
#pragma unroll
    for (int r = 0; r < 4; r++) {
      const int e2 = s_e2lo + r * 16;
      {
        const uint32_t a0 = V32[tokbase + (e0 >> 1) + e2];
        const uint32_t a1 = V32[tokbase + 128 + (e0 >> 1) + e2];
        *(uint32_t*)(Asm + (2 * e2) * 80 + 4 * s_np)     = (a0 & 0xffffu) | (a1 << 16);
        *(uint32_t*)(Asm + (2 * e2 + 1) * 80 + 4 * s_np) = (a0 >> 16) | (a1 & 0xffff0000u);
      }
      {
        const uint32_t b0 = K32[tokbase + (d0 >> 1) + e2];
        const uint32_t b1 = K32[tokbase + 128 + (d0 >> 1) + e2];
        *(uint32_t*)(Bsm + (2 * e2) * 80 + 4 * s_np)     = (b0 & 0xffffu) | (b1 << 16);
        *(uint32_t*)(Bsm + (2 * e2 + 1) * 80 + 4 * s_np) = (b0 >> 16) | (b1 & 0xffff0000u);
      }
    }
    __syncthreads();
    short8 af[4], bf8[4];
#pragma unroll
    for (int i = 0; i < 4; i++) {
      af[i]  = *(const short8*)(Asm + (wm + i * 16 + l16) * 80 + q4 * 16);
      bf8[i] = *(const short8*)(Bsm + (wn + i * 16 + l16) * 80 + q4 * 16);
    }
#pragma unroll
    for (int i = 0; i < 4; i++)
#pragma unroll
      for (int j = 0; j < 4; j++)
        acc[i][j] = __builtin_amdgcn_mfma_f32_16x16x32_bf16(af[i], bf8[j], acc[i][j], 0, 0, 0);
    __syncthreads();
  }
  __hip_bfloat16* pt = part + (((size_t)(chunk * 4 + b)) << 16);
#pragma unroll
  for (int i = 0; i < 4; i++) {
#pragma unroll
    for (int r = 0; r < 4; r++) {
      const int eg = e0 + wm + i * 16 + q4 * 4 + r;
#pragma unroll
      for (int j = 0; j < 4; j++) {
        const int dg = d0 + wn + j * 16 + l16;
        pt[eg * 256 + dg] = __float2bfloat16(acc[i][j][r]);
      }
    }
  }
}

// ---------------- Kernel 4: P[b] = bf16( sum_chunks part[chunk][b] )  (bf16 in) -------------
__global__ __launch_bounds__(256) void reduce_kvt(const uint32_t* __restrict__ part,
                                                  uint32_t* __restrict__ P) {
  const int flat2 = blockIdx.x * 256 + threadIdx.x;  // dword index over [4][32768]
  const int b = flat2 >> 15;
  const int off = flat2 & 32767;
  float sx = 0, sy = 0;
#pragma unroll
  for (int c = 0; c < 32; c++) {
    const uint32_t u = part[(((size_t)(c * 4 + b)) << 15) + off];
    sx += bflo(u); sy += bfhi(u);
  }
  P[flat2] = packbf(sx, sy);
}

// ---------------- Kernel 5: out = q_rot @ P^T + bo  (fp32 out to d_out) ---------------------
__global__ __launch_bounds__(256, 2) void gemm_out(
    const __hip_bfloat16* __restrict__ A, const __hip_bfloat16* __restrict__ Pm,
    const float* __restrict__ bo, float* __restrict__ Og) {
  __shared__ __align__(16) char As[8192];
  __shared__ __align__(16) char Bs[8192];
  const int t = threadIdx.x, lane = t & 63, wid = t >> 6;
  const int wm = (wid & 1) * 64, wn = (wid >> 1) * 64;
  const int l16 = lane & 15, q4 = lane >> 4;
  const int m0 = blockIdx.x * 128, n0 = blockIdx.y * 128;
  const int b = m0 >> 13;
  const __hip_bfloat16* W = Pm + ((size_t)b << 16);
  floatx4 acc[4][4] = {};
  const int srow = wid * 16 + (lane >> 2);
  const int skoff = (lane & 3) * 8;
  const __hip_bfloat16* gA = A + (size_t)(m0 + srow) * D + skoff;
  const __hip_bfloat16* gB = W + (size_t)(n0 + srow) * D + skoff;
  char* lA = As + srow * 64 + skoff * 2;
  char* lB = Bs + srow * 64 + skoff * 2;
  for (int kt = 0; kt < 256; kt += 32) {
    gl_lds16(gA + kt, lA);
    gl_lds16(gA + kt + 64 * D, lA + 4096);
    gl_lds16(gB + kt, lB);
    gl_lds16(gB + kt + 64 * D, lB + 4096);
    __syncthreads();
    short8 af[4], bf8[4];
#pragma unroll
    for (int i = 0; i < 4; i++) {
      af[i]  = *(const short8*)(As + (wm + i * 16 + l16) * 64 + q4 * 16);
      bf8[i] = *(const short8*)(Bs + (wn + i * 16 + l16) * 64 + q4 * 16);
    }
#pragma unroll
    for (int i = 0; i < 4; i++)
#pragma unroll
      for (int j = 0; j < 4; j++)
        acc[i][j] = __builtin_amdgcn_mfma_f32_16x16x32_bf16(af[i], bf8[j], acc[i][j], 0, 0, 0);
    __syncthreads();
  }
#pragma unroll
  for (int j = 0; j < 4; j++) {
    const int colg = n0 + wn + j * 16 + l16;
    const float bb = bo[colg];
#pragma unroll
    for (int i = 0; i < 4; i++) {
      const int rowg = m0 + wm + i * 16 + q4 * 4;
#pragma unroll
      for (int r = 0; r < 4; r++)
        Og[(size_t)(rowg + r) * D + colg] = acc[i][j][r] + bb;
    }
  }
}

extern "C" void kernel_launch(void* const* d_in, const int* in_sizes, int n_in,
                              void* d_out, int out_size, void* d_ws, size_t ws_size,
                              hipStream_t stream) {
  const float* phi    = (const float*)d_in[0];
  const float* coords = (const float*)d_in[1];
  const float* wts    = (const float*)d_in[2];
  const float* bq     = (const float*)d_in[4];
  const float* bk     = (const float*)d_in[6];
  const float* bv     = (const float*)d_in[8];
  const float* Wo     = (const float*)d_in[9];
  const float* bo     = (const float*)d_in[10];
  const float* lift   = (const float*)d_in[11];

  char* ws = (char*)d_ws;
  __hip_bfloat16* phi16 = (__hip_bfloat16*)ws;            // 16 MiB
  __hip_bfloat16* W16   = (__hip_bfloat16*)(ws + 16777216);
  const size_t QOFF = 17170432;
  const size_t SZ = (size_t)MTOT * D * 2;  // 16 MiB per bf16 buffer
  __hip_bfloat16* Qb = (__hip_bfloat16*)(ws + QOFF);
  __hip_bfloat16* Kb = (__hip_bfloat16*)(ws + QOFF + SZ);
  __hip_bfloat16* Vb = (__hip_bfloat16*)(ws + QOFF + 2 * SZ);
  const size_t NOFF = QOFF + 3 * SZ;       // 67502080
  float* nsk = (float*)(ws + NOFF);
  float* nsv = (float*)(ws + NOFF + 4096);
  __hip_bfloat16* part = (__hip_bfloat16*)(ws + NOFF + 8192);              // 16 MiB bf16
  __hip_bfloat16* P = (__hip_bfloat16*)(ws + NOFF + 8192 + 16777216);      // 512 KiB
  __hip_bfloat16* vproj = (__hip_bfloat16*)(ws + NOFF + 8192 + 16777216 + 524288);  // 16 MiB

  convert<<<16768, 256, 0, stream>>>(phi, (const float*)d_in[3], (const float*)d_in[5],
                                     (const float*)d_in[7], (uint32_t*)ws, (float2*)(ws + NOFF));
  gemm_qkv<<<dim3(256, 3), 256, 0, stream>>>(phi16, W16, bq, bk, bv, coords, wts, lift,
                                             Qb, Kb, Vb, nsk, nsv);
  vproj_pk<<<640, 256, 0, stream>>>(Vb, Wo, nsv, vproj, Kb, coords, wts, lift, nsk);
  gemm_tn<<<dim3(32, 4, 4), 256, 0, stream>>>(vproj, Kb, part);
  reduce_kvt<<<512, 256, 0, stream>>>((const uint32_t*)part, (uint32_t*)P);
  gemm_out<<<dim3(256, 2), 256, 0, stream>>>(Qb, P, bo, (float*)d_out);
}